// Round 15
// baseline (681.210 us; speedup 1.0000x reference)
//
#include <hip/hip_runtime.h>
#include <hip/hip_bf16.h>

#define D_ 128
#define L_ 65536
#define C_ 32768
#define E_ 262144

typedef __hip_bfloat16 bf16;
typedef __attribute__((ext_vector_type(8))) short short8;
typedef __attribute__((ext_vector_type(4))) float f32x4;

// flags[0] = 1 if float inputs are fp32 (else bf16); flags[1] = 1 if edge idx int32 (else int64)
__global__ void detect_k(const unsigned short* __restrict__ wmem,
                         const int* __restrict__ li, int* __restrict__ flags) {
    int t = blockIdx.x * 512 + threadIdx.x;
    if (t < 8192) {
        unsigned short h = wmem[2 * t];
        float v = __bfloat162float(*(const bf16*)&h);
        if (!(fabsf(v) < 0.5f)) atomicOr(&flags[0], 1);
    }
    if (t < 2048) {
        if (li[2 * t + 1] != 0) atomicOr(&flags[1], 1);
    }
}

__device__ __forceinline__ void split2(float v, unsigned short& h, unsigned short& l) {
    bf16 bh = __float2bfloat16(v);
    float fh = __bfloat162float(bh);
    bf16 bl = __float2bfloat16(v - fh);
    h = *(unsigned short*)&bh;
    l = *(unsigned short*)&bl;
}

__device__ __forceinline__ float ldf(const void* s, int i, int isf32) {
    return isf32 ? ((const float*)s)[i] : __bfloat162float(((const bf16*)s)[i]);
}

// ---- fused preamble: fixdeg (2048 blocks) + cvtwb (708) + tile-0 init2 (32) ----
__global__ void prep_k(const int* __restrict__ ls, const int* __restrict__ cs,
                       int* __restrict__ ld_idx, int* __restrict__ cd_idx,
                       int* __restrict__ ldeg, int* __restrict__ cdeg,
                       const void* s0, const void* s1, const void* s2, const void* s3,
                       const void* s4, const void* s5, const void* s6, const void* s7,
                       const void* t0, const void* t1, const void* t2, const void* t3,
                       const void* t4, const void* t5, const void* t6, const void* t7,
                       unsigned short* __restrict__ hi, unsigned short* __restrict__ lo,
                       float* __restrict__ bb,
                       const void* __restrict__ lv, const void* __restrict__ cv,
                       float* __restrict__ lemb, float* __restrict__ cemb,
                       const int* __restrict__ flags) {
    const int blk = blockIdx.x;
    const int isf = flags[0];
    if (blk < 2048) {
        int i = blk * 256 + threadIdx.x;
        int is32 = flags[1];
        if (i < E_) {
            int v = is32 ? ls[i] : ls[2 * i];
            v = min(max(v, 0), L_ - 1);
            ld_idx[i] = v;
            atomicAdd(&ldeg[v], 1);
        } else {
            int j = i - E_;
            int v = is32 ? cs[j] : cs[2 * j];
            v = min(max(v, 0), C_ - 1);
            cd_idx[j] = v;
            atomicAdd(&cdeg[v], 1);
        }
        return;
    }
    if (blk < 2756) {
        int i = (blk - 2048) * 256 + threadIdx.x;  // 181248 total
        if (i >= 180224) {
            int j = i - 180224;  // 0..1023
            const void* src;
            switch (j >> 7) {
                case 0: src = t0; break; case 1: src = t1; break;
                case 2: src = t2; break; case 3: src = t3; break;
                case 4: src = t4; break; case 5: src = t5; break;
                case 6: src = t6; break; default: src = t7; break;
            }
            bb[j] = ldf(src, j & 127, isf);
            return;
        }
        const void* src; int K, base;
        if      (i <  16384) { src = s0; K = 128; base = 0; }
        else if (i <  32768) { src = s1; K = 128; base = 16384; }
        else if (i <  49152) { src = s2; K = 128; base = 32768; }
        else if (i <  65536) { src = s3; K = 128; base = 49152; }
        else if (i <  81920) { src = s4; K = 128; base = 65536; }
        else if (i <  98304) { src = s5; K = 128; base = 81920; }
        else if (i < 131072) { src = s6; K = 256; base = 98304; }
        else                 { src = s7; K = 384; base = 131072; }
        int e = i - base;
        int k = e >> 7, n = e & 127;
        float v = ldf(src, e, isf);
        unsigned short h, l;
        split2(v, h, l);
        hi[base + n * K + k] = h;
        lo[base + n * K + k] = l;
        return;
    }
    // ---- init2 (tile 0 only): blocks [2756, 2788) -> 8192 float4 writes ----
    int i4 = (blk - 2756) * 256 + threadIdx.x;  // 0..8191
    const void* src; float* dst; int o;
    if (i4 < 4096) { src = lv; dst = lemb; o = i4; }       // l rows 0..127
    else           { src = cv; dst = cemb; o = i4 - 4096; } // c rows 0..127
    int j = (o & 31) * 4;
    float4 v;
    v.x = ldf(src, j + 0, isf);
    v.y = ldf(src, j + 1, isf);
    v.z = ldf(src, j + 2, isf);
    v.w = ldf(src, j + 3, isf);
    ((float4*)dst)[o] = v;
}

// --- per-tile exclusive scan (stage 1), both sides fused ---
__global__ void scan1b_k(const int* __restrict__ ldeg, const int* __restrict__ cdeg,
                         int* __restrict__ lout, int* __restrict__ cout,
                         int* __restrict__ bsumL, int* __restrict__ bsumC) {
    __shared__ int s[256];
    const int* in; int* out; int* bs; int tile;
    if (blockIdx.x < 256) { in = ldeg; out = lout; bs = bsumL; tile = blockIdx.x; }
    else                  { in = cdeg; out = cout; bs = bsumC; tile = blockIdx.x - 256; }
    int i = tile * 256 + threadIdx.x;
    int v = in[i];
    s[threadIdx.x] = v;
    __syncthreads();
#pragma unroll
    for (int off = 1; off < 256; off <<= 1) {
        int t = (threadIdx.x >= off) ? s[threadIdx.x - off] : 0;
        __syncthreads();
        s[threadIdx.x] += t;
        __syncthreads();
    }
    out[i] = s[threadIdx.x] - v;
    if (threadIdx.x == 255) bs[tile] = s[255];
}

// stage 2+3 fused: each block redundantly computes its own bsum prefix.
__global__ void scan3b_k(int* __restrict__ lptr, int* __restrict__ cptr,
                         const int* __restrict__ bsumL, const int* __restrict__ bsumC,
                         int* __restrict__ lcur, int* __restrict__ ccur,
                         const int* __restrict__ ldeg, const int* __restrict__ cdeg,
                         float* __restrict__ invsq_l, float* __restrict__ invsq_c) {
    __shared__ int sh[256];
    int b = blockIdx.x, t = threadIdx.x;
    const bool lside = (b < 256);
    const int tile = lside ? b : b - 256;
    const int* bs = lside ? bsumL : bsumC;
    sh[t] = (t < tile) ? bs[t] : 0;
    __syncthreads();
#pragma unroll
    for (int off = 128; off > 0; off >>= 1) {
        if (t < off) sh[t] += sh[t + off];
        __syncthreads();
    }
    const int pref = sh[0];
    int i = tile * 256 + t;
    if (lside) {
        int v = lptr[i] + pref;
        lptr[i] = v; lcur[i] = v;
        int d = ldeg[i];
        invsq_l[i] = d ? rsqrtf((float)d) : 0.0f;
    } else {
        int v = cptr[i] + pref;
        cptr[i] = v; ccur[i] = v;
        int d = cdeg[i];
        invsq_c[i] = d ? rsqrtf((float)d) : 0.0f;
    }
}

// CSR placement (other endpoint only; norm is separable)
__global__ void place_k(const int* __restrict__ li, const int* __restrict__ ci,
                        int* __restrict__ lcur, int* __restrict__ ccur,
                        int* __restrict__ l_other, int* __restrict__ c_other) {
    int e = blockIdx.x * 256 + threadIdx.x;
    if (e >= E_) return;
    int l = li[e], c = ci[e];
    int p = atomicAdd(&ccur[c], 1);
    c_other[p] = l;
    int q = atomicAdd(&lcur[l], 1);
    l_other[q] = c;
}

// it=0: l2l rows 0..127 only (sole reader is uconst_k pass 2). 8 blocks.
__global__ void bcast_k(const float* __restrict__ baseb, bf16* __restrict__ l2lb) {
    int id = blockIdx.x * 256 + threadIdx.x;   // 2048 ids, each writes 8 bf16
    const float* base = baseb + 256;
    int row = id >> 4, c8 = (id & 15) * 8;
    union { short8 v; unsigned short u[8]; } o;
#pragma unroll
    for (int k = 0; k < 8; k++) {
        bf16 b = __float2bfloat16(base[c8 + k]);
        o.u[k] = *(unsigned short*)&b;
    }
    *(short8*)&l2lb[(size_t)row * D_ + c8] = o.v;
}

// it=0 gather: messages are rank-1; synthesize in-register (r14 structure).
__global__ __launch_bounds__(256) void gather0_k(
    const int* __restrict__ cptr, const int* __restrict__ cdeg, const int* __restrict__ c_other,
    const float* __restrict__ baseb,
    const float* __restrict__ invsq_l, const float* __restrict__ invsq_c,
    float* __restrict__ caggr,
    const int* __restrict__ lptr, const int* __restrict__ ldeg, const int* __restrict__ l_other,
    float* __restrict__ laggr, int nC) {
    int wid = (blockIdx.x * 256 + threadIdx.x) >> 6;
    int lane = threadIdx.x & 63;
    int n0 = 4 * wid;
    bool cside = n0 < nC;
    int j0 = cside ? n0 : n0 - nC;
    const int* ptr = cside ? cptr : lptr;
    const int* dg  = cside ? cdeg : ldeg;
    const int* oth = cside ? c_other : l_other;
    const float* isrc = cside ? invsq_l : invsq_c;      // SOURCE-side scale
    const float* invsq = cside ? invsq_c : invsq_l;     // dest-side scale
    const float* base = baseb + (cside ? 0 : 128);      // l2c base / c2l base
    float* out = cside ? caggr : laggr;
    const float b0 = base[2 * lane], b1 = base[2 * lane + 1];

    int s0 = ptr[j0],     c0 = dg[j0];
    int s1 = ptr[j0 + 1], c1 = dg[j0 + 1];
    int s2 = ptr[j0 + 2], c2 = dg[j0 + 2];
    int s3 = ptr[j0 + 3], c3 = dg[j0 + 3];
    float2 A0 = {0.f, 0.f}, B0 = {0.f, 0.f};
    float2 A1 = {0.f, 0.f}, B1 = {0.f, 0.f};
    float2 A2 = {0.f, 0.f}, B2 = {0.f, 0.f};
    float2 A3 = {0.f, 0.f}, B3 = {0.f, 0.f};
    int k0 = 0, k1 = 0, k2 = 0, k3 = 0;

#define GSC_(s, k) isrc[oth[(s) + (k)]]
#define GACCs_(a, sc) { (a).x += __bfloat162float(__float2bfloat16(b0 * (sc))); \
                        (a).y += __bfloat162float(__float2bfloat16(b1 * (sc))); }

    for (; k0 + 2 <= c0 && k1 + 2 <= c1 && k2 + 2 <= c2 && k3 + 2 <= c3;
         k0 += 2, k1 += 2, k2 += 2, k3 += 2) {
        float sc00 = GSC_(s0, k0), sc01 = GSC_(s0, k0 + 1);
        float sc10 = GSC_(s1, k1), sc11 = GSC_(s1, k1 + 1);
        float sc20 = GSC_(s2, k2), sc21 = GSC_(s2, k2 + 1);
        float sc30 = GSC_(s3, k3), sc31 = GSC_(s3, k3 + 1);
        GACCs_(A0, sc00); GACCs_(B0, sc01);
        GACCs_(A1, sc10); GACCs_(B1, sc11);
        GACCs_(A2, sc20); GACCs_(B2, sc21);
        GACCs_(A3, sc30); GACCs_(B3, sc31);
    }
    for (; k0 + 2 <= c0 && k1 + 2 <= c1; k0 += 2, k1 += 2) {
        float sc00 = GSC_(s0, k0), sc01 = GSC_(s0, k0 + 1);
        float sc10 = GSC_(s1, k1), sc11 = GSC_(s1, k1 + 1);
        GACCs_(A0, sc00); GACCs_(B0, sc01);
        GACCs_(A1, sc10); GACCs_(B1, sc11);
    }
    for (; k2 + 2 <= c2 && k3 + 2 <= c3; k2 += 2, k3 += 2) {
        float sc20 = GSC_(s2, k2), sc21 = GSC_(s2, k2 + 1);
        float sc30 = GSC_(s3, k3), sc31 = GSC_(s3, k3 + 1);
        GACCs_(A2, sc20); GACCs_(B2, sc21);
        GACCs_(A3, sc30); GACCs_(B3, sc31);
    }
    for (; k0 + 2 <= c0; k0 += 2) {
        float sa = GSC_(s0, k0), sb = GSC_(s0, k0 + 1);
        GACCs_(A0, sa); GACCs_(B0, sb);
    }
    for (; k1 + 2 <= c1; k1 += 2) {
        float sa = GSC_(s1, k1), sb = GSC_(s1, k1 + 1);
        GACCs_(A1, sa); GACCs_(B1, sb);
    }
    for (; k2 + 2 <= c2; k2 += 2) {
        float sa = GSC_(s2, k2), sb = GSC_(s2, k2 + 1);
        GACCs_(A2, sa); GACCs_(B2, sb);
    }
    for (; k3 + 2 <= c3; k3 += 2) {
        float sa = GSC_(s3, k3), sb = GSC_(s3, k3 + 1);
        GACCs_(A3, sa); GACCs_(B3, sb);
    }
    if (k0 < c0) { float sa = GSC_(s0, k0); GACCs_(A0, sa); }
    if (k1 < c1) { float sa = GSC_(s1, k1); GACCs_(A1, sa); }
    if (k2 < c2) { float sa = GSC_(s2, k2); GACCs_(A2, sa); }
    if (k3 < c3) { float sa = GSC_(s3, k3); GACCs_(A3, sa); }
#undef GSC_
#undef GACCs_

    float sc0 = invsq[j0], sc1 = invsq[j0 + 1];
    float sc2 = invsq[j0 + 2], sc3 = invsq[j0 + 3];
    float2 r;
    r.x = (A0.x + B0.x) * sc0; r.y = (A0.y + B0.y) * sc0;
    *(float2*)&out[(size_t)j0 * D_ + 2 * lane] = r;
    r.x = (A1.x + B1.x) * sc1; r.y = (A1.y + B1.y) * sc1;
    *(float2*)&out[(size_t)(j0 + 1) * D_ + 2 * lane] = r;
    r.x = (A2.x + B2.x) * sc2; r.y = (A2.y + B2.y) * sc2;
    *(float2*)&out[(size_t)(j0 + 2) * D_ + 2 * lane] = r;
    r.x = (A3.x + B3.x) * sc3; r.y = (A3.y + B3.y) * sc3;
    *(float2*)&out[(size_t)(j0 + 3) * D_ + 2 * lane] = r;
}

// it=0 uniform-range constants for update (runs EXACT update_k staging+MFMA
// sequence on tile 0 for the row-uniform K ranges; stores row 0's acc).
__global__ __launch_bounds__(256, 2) void uconst_k(
    const float* __restrict__ l_cur, const float* __restrict__ c_cur,
    const bf16* __restrict__ l2lb,
    const unsigned short* __restrict__ wt_hi, const unsigned short* __restrict__ wt_lo,
    float* __restrict__ uc) {
    __shared__ unsigned short a_hi[128][40], a_lo[128][40];
    __shared__ unsigned short b_hi[128][40], b_lo[128][40];
    const int t = threadIdx.x;
    const bool cseg = (blockIdx.x == 0);
    const int K = cseg ? 256 : 384;
    const float* A0 = cseg ? c_cur : l_cur;
    const unsigned short* Wh = wt_hi + (cseg ? 98304 : 131072);
    const unsigned short* Wl = wt_lo + (cseg ? 98304 : 131072);
    const int w = t >> 6, lane = t & 63;
    const int wr = w >> 1, wc = w & 1;
    const int quad = lane >> 4, cl = lane & 15;

    f32x4 acc[4][4];
#pragma unroll
    for (int i = 0; i < 4; i++)
#pragma unroll
        for (int j = 0; j < 4; j++) acc[i][j] = (f32x4){0.f, 0.f, 0.f, 0.f};

    for (int kt = 0; kt < 128; kt += 32) {
#pragma unroll
        for (int i = 0; i < 4; i++) {
            int f = t + 256 * i;
            int r = f >> 3, kq = f & 7;
            const float4 v = *(const float4*)&A0[(size_t)r * D_ + kt + 4 * kq];
            unsigned short h0, l0, h1, l1, h2, l2, h3, l3;
            split2(v.x, h0, l0); split2(v.y, h1, l1);
            split2(v.z, h2, l2); split2(v.w, h3, l3);
            *(ushort4*)&a_hi[r][4 * kq] = make_ushort4(h0, h1, h2, h3);
            *(ushort4*)&a_lo[r][4 * kq] = make_ushort4(l0, l1, l2, l3);
            *(ushort4*)&b_hi[r][4 * kq] = *(const ushort4*)&Wh[(size_t)r * K + kt + 4 * kq];
            *(ushort4*)&b_lo[r][4 * kq] = *(const ushort4*)&Wl[(size_t)r * K + kt + 4 * kq];
        }
        __syncthreads();
        short8 af_h[4], af_l[4];
#pragma unroll
        for (int i = 0; i < 4; i++) {
            int row = 64 * wr + 16 * i + cl;
            af_h[i] = *(const short8*)&a_hi[row][quad * 8];
            af_l[i] = *(const short8*)&a_lo[row][quad * 8];
        }
#pragma unroll
        for (int j = 0; j < 4; j++) {
            int col = 64 * wc + 16 * j + cl;
            short8 bf_h = *(const short8*)&b_hi[col][quad * 8];
            short8 bf_l = *(const short8*)&b_lo[col][quad * 8];
#pragma unroll
            for (int i = 0; i < 4; i++) {
                acc[i][j] = __builtin_amdgcn_mfma_f32_16x16x32_bf16(af_h[i], bf_h, acc[i][j], 0, 0, 0);
                acc[i][j] = __builtin_amdgcn_mfma_f32_16x16x32_bf16(af_h[i], bf_l, acc[i][j], 0, 0, 0);
                acc[i][j] = __builtin_amdgcn_mfma_f32_16x16x32_bf16(af_l[i], bf_h, acc[i][j], 0, 0, 0);
            }
        }
        __syncthreads();
    }
#pragma unroll
    for (int j = 0; j < 4; j++) {
        int col = 64 * wc + 16 * j + cl;
        if (w < 2 && lane < 16) uc[(cseg ? 0 : 128) + col] = acc[0][j][0];
    }
    if (cseg) return;

    // pass 2: l2l tiles kt=256..383 accumulated from zero (bf16 hi-plane only)
#pragma unroll
    for (int i = 0; i < 4; i++)
#pragma unroll
        for (int j = 0; j < 4; j++) acc[i][j] = (f32x4){0.f, 0.f, 0.f, 0.f};
    for (int kt = 256; kt < 384; kt += 32) {
        const int koff = kt & 127;
#pragma unroll
        for (int i = 0; i < 4; i++) {
            int f = t + 256 * i;
            int r = f >> 3, kq = f & 7;
            *(ushort4*)&a_hi[r][4 * kq] =
                *(const ushort4*)&l2lb[(size_t)r * D_ + koff + 4 * kq];
            *(ushort4*)&b_hi[r][4 * kq] = *(const ushort4*)&Wh[(size_t)r * K + kt + 4 * kq];
            *(ushort4*)&b_lo[r][4 * kq] = *(const ushort4*)&Wl[(size_t)r * K + kt + 4 * kq];
        }
        __syncthreads();
        short8 af_h[4];
#pragma unroll
        for (int i = 0; i < 4; i++) {
            int row = 64 * wr + 16 * i + cl;
            af_h[i] = *(const short8*)&a_hi[row][quad * 8];
        }
#pragma unroll
        for (int j = 0; j < 4; j++) {
            int col = 64 * wc + 16 * j + cl;
            short8 bf_h = *(const short8*)&b_hi[col][quad * 8];
            short8 bf_l = *(const short8*)&b_lo[col][quad * 8];
#pragma unroll
            for (int i = 0; i < 4; i++) {
                acc[i][j] = __builtin_amdgcn_mfma_f32_16x16x32_bf16(af_h[i], bf_h, acc[i][j], 0, 0, 0);
                acc[i][j] = __builtin_amdgcn_mfma_f32_16x16x32_bf16(af_h[i], bf_l, acc[i][j], 0, 0, 0);
            }
        }
        __syncthreads();
    }
#pragma unroll
    for (int j = 0; j < 4; j++) {
        int col = 64 * wc + 16 * j + cl;
        if (w < 2 && lane < 16) uc[256 + col] = acc[0][j][0];
    }
}

// it=0 update: acc from uniform-range constants; only the 4 aggregate K-tiles.
// (256,4): 40KB LDS allows 4 independent blocks/CU -- anti-phase overlap.
__global__ __launch_bounds__(256, 4) void update0_k(
    const float* __restrict__ laggr, const float* __restrict__ caggr,
    const unsigned short* __restrict__ wt_hi, const unsigned short* __restrict__ wt_lo,
    const float* __restrict__ bb, const float* __restrict__ uc,
    float* __restrict__ c_nxt, float* __restrict__ l_nxt) {
    __shared__ unsigned short a_hi[128][40], a_lo[128][40];
    __shared__ unsigned short b_hi[128][40], b_lo[128][40];
    const int t = threadIdx.x;
    int b = blockIdx.x;
    const bool cseg = (b < 256);
    const int tile = cseg ? b : b - 256;
    const int K = cseg ? 256 : 384;
    const float* A1 = cseg ? caggr : laggr;
    const unsigned short* Wh = wt_hi + (cseg ? 98304 : 131072);
    const unsigned short* Wl = wt_lo + (cseg ? 98304 : 131072);
    const float* bias = bb + (cseg ? 768 : 896);
    const float* uc0 = uc + (cseg ? 0 : 128);
    const int br0 = tile * 128;
    const int w = t >> 6, lane = t & 63;
    const int wr = w >> 1, wc = w & 1;
    const int quad = lane >> 4, cl = lane & 15;

    f32x4 acc[4][4];
#pragma unroll
    for (int j = 0; j < 4; j++) {
        int col = 64 * wc + 16 * j + cl;
        float cv = uc0[col];
#pragma unroll
        for (int i = 0; i < 4; i++) acc[i][j] = (f32x4){cv, cv, cv, cv};
    }

    for (int kt = 128; kt < 256; kt += 32) {
        const int koff = kt & 127;
#pragma unroll
        for (int i = 0; i < 4; i++) {
            int f = t + 256 * i;
            int r = f >> 3, kq = f & 7;
            const float4 v = *(const float4*)&A1[(size_t)(br0 + r) * D_ + koff + 4 * kq];
            unsigned short h0, l0, h1, l1, h2, l2, h3, l3;
            split2(v.x, h0, l0); split2(v.y, h1, l1);
            split2(v.z, h2, l2); split2(v.w, h3, l3);
            *(ushort4*)&a_hi[r][4 * kq] = make_ushort4(h0, h1, h2, h3);
            *(ushort4*)&a_lo[r][4 * kq] = make_ushort4(l0, l1, l2, l3);
            *(ushort4*)&b_hi[r][4 * kq] = *(const ushort4*)&Wh[(size_t)r * K + kt + 4 * kq];
            *(ushort4*)&b_lo[r][4 * kq] = *(const ushort4*)&Wl[(size_t)r * K + kt + 4 * kq];
        }
        __syncthreads();
        short8 af_h[4], af_l[4];
#pragma unroll
        for (int i = 0; i < 4; i++) {
            int row = 64 * wr + 16 * i + cl;
            af_h[i] = *(const short8*)&a_hi[row][quad * 8];
            af_l[i] = *(const short8*)&a_lo[row][quad * 8];
        }
#pragma unroll
        for (int j = 0; j < 4; j++) {
            int col = 64 * wc + 16 * j + cl;
            short8 bf_h = *(const short8*)&b_hi[col][quad * 8];
            short8 bf_l = *(const short8*)&b_lo[col][quad * 8];
#pragma unroll
            for (int i = 0; i < 4; i++) {
                acc[i][j] = __builtin_amdgcn_mfma_f32_16x16x32_bf16(af_h[i], bf_h, acc[i][j], 0, 0, 0);
                acc[i][j] = __builtin_amdgcn_mfma_f32_16x16x32_bf16(af_h[i], bf_l, acc[i][j], 0, 0, 0);
                acc[i][j] = __builtin_amdgcn_mfma_f32_16x16x32_bf16(af_l[i], bf_h, acc[i][j], 0, 0, 0);
            }
        }
        __syncthreads();
    }
    float* outp = cseg ? c_nxt : l_nxt;
#pragma unroll
    for (int j = 0; j < 4; j++) {
        int col = 64 * wc + 16 * j + cl;
        float bv = bias[col];
        float l2lc = cseg ? 0.0f : uc[256 + col];
#pragma unroll
        for (int i = 0; i < 4; i++) {
            int rbase = br0 + 64 * wr + 16 * i + quad * 4;
#pragma unroll
            for (int rg = 0; rg < 4; rg++) {
                float v = (acc[i][j][rg] + l2lc) + bv;
                outp[(size_t)(rbase + rg) * D_ + col] = v;
            }
        }
    }
}

// Fused pull-aggregation, both directions (r9 4-node/2-deep structure, kept).
__global__ __launch_bounds__(256) void gather2_k(
    const int* __restrict__ cptr, const int* __restrict__ cdeg, const int* __restrict__ c_other,
    const unsigned int* __restrict__ lmsg, const float* __restrict__ invsq_c, float* __restrict__ caggr,
    const int* __restrict__ lptr, const int* __restrict__ ldeg, const int* __restrict__ l_other,
    const unsigned int* __restrict__ cmsg, const float* __restrict__ invsq_l, float* __restrict__ laggr,
    int nC) {
    int wid = (blockIdx.x * 256 + threadIdx.x) >> 6;
    int lane = threadIdx.x & 63;
    int n0 = 4 * wid;
    bool cside = n0 < nC;
    int j0 = cside ? n0 : n0 - nC;
    const int* ptr = cside ? cptr : lptr;
    const int* dg  = cside ? cdeg : ldeg;
    const int* oth = cside ? c_other : l_other;
    const unsigned int* msg = cside ? lmsg : cmsg;
    const float* invsq = cside ? invsq_c : invsq_l;
    float* out = cside ? caggr : laggr;

    int s0 = ptr[j0],     c0 = dg[j0];
    int s1 = ptr[j0 + 1], c1 = dg[j0 + 1];
    int s2 = ptr[j0 + 2], c2 = dg[j0 + 2];
    int s3 = ptr[j0 + 3], c3 = dg[j0 + 3];
    float2 A0 = {0.f, 0.f}, B0 = {0.f, 0.f};
    float2 A1 = {0.f, 0.f}, B1 = {0.f, 0.f};
    float2 A2 = {0.f, 0.f}, B2 = {0.f, 0.f};
    float2 A3 = {0.f, 0.f}, B3 = {0.f, 0.f};
    int k0 = 0, k1 = 0, k2 = 0, k3 = 0;

#define GLD_(s, k) msg[(size_t)oth[(s) + (k)] * 64 + lane]
#define GACC_(a, u) { (a).x += __uint_as_float((u) << 16); \
                      (a).y += __uint_as_float((u) & 0xffff0000u); }

    for (; k0 + 2 <= c0 && k1 + 2 <= c1 && k2 + 2 <= c2 && k3 + 2 <= c3;
         k0 += 2, k1 += 2, k2 += 2, k3 += 2) {
        unsigned int u00 = GLD_(s0, k0), u01 = GLD_(s0, k0 + 1);
        unsigned int u10 = GLD_(s1, k1), u11 = GLD_(s1, k1 + 1);
        unsigned int u20 = GLD_(s2, k2), u21 = GLD_(s2, k2 + 1);
        unsigned int u30 = GLD_(s3, k3), u31 = GLD_(s3, k3 + 1);
        GACC_(A0, u00); GACC_(B0, u01);
        GACC_(A1, u10); GACC_(B1, u11);
        GACC_(A2, u20); GACC_(B2, u21);
        GACC_(A3, u30); GACC_(B3, u31);
    }
    for (; k0 + 2 <= c0 && k1 + 2 <= c1; k0 += 2, k1 += 2) {
        unsigned int u00 = GLD_(s0, k0), u01 = GLD_(s0, k0 + 1);
        unsigned int u10 = GLD_(s1, k1), u11 = GLD_(s1, k1 + 1);
        GACC_(A0, u00); GACC_(B0, u01);
        GACC_(A1, u10); GACC_(B1, u11);
    }
    for (; k2 + 2 <= c2 && k3 + 2 <= c3; k2 += 2, k3 += 2) {
        unsigned int u20 = GLD_(s2, k2), u21 = GLD_(s2, k2 + 1);
        unsigned int u30 = GLD_(s3, k3), u31 = GLD_(s3, k3 + 1);
        GACC_(A2, u20); GACC_(B2, u21);
        GACC_(A3, u30); GACC_(B3, u31);
    }
    for (; k0 + 2 <= c0; k0 += 2) {
        unsigned int ua = GLD_(s0, k0), ub = GLD_(s0, k0 + 1);
        GACC_(A0, ua); GACC_(B0, ub);
    }
    for (; k1 + 2 <= c1; k1 += 2) {
        unsigned int ua = GLD_(s1, k1), ub = GLD_(s1, k1 + 1);
        GACC_(A1, ua); GACC_(B1, ub);
    }
    for (; k2 + 2 <= c2; k2 += 2) {
        unsigned int ua = GLD_(s2, k2), ub = GLD_(s2, k2 + 1);
        GACC_(A2, ua); GACC_(B2, ub);
    }
    for (; k3 + 2 <= c3; k3 += 2) {
        unsigned int ua = GLD_(s3, k3), ub = GLD_(s3, k3 + 1);
        GACC_(A3, ua); GACC_(B3, ub);
    }
    if (k0 < c0) { unsigned int u = GLD_(s0, k0); GACC_(A0, u); }
    if (k1 < c1) { unsigned int u = GLD_(s1, k1); GACC_(A1, u); }
    if (k2 < c2) { unsigned int u = GLD_(s2, k2); GACC_(A2, u); }
    if (k3 < c3) { unsigned int u = GLD_(s3, k3); GACC_(A3, u); }
#undef GLD_
#undef GACC_

    float sc0 = invsq[j0], sc1 = invsq[j0 + 1];
    float sc2 = invsq[j0 + 2], sc3 = invsq[j0 + 3];
    float2 r;
    r.x = (A0.x + B0.x) * sc0; r.y = (A0.y + B0.y) * sc0;
    *(float2*)&out[(size_t)j0 * D_ + 2 * lane] = r;
    r.x = (A1.x + B1.x) * sc1; r.y = (A1.y + B1.y) * sc1;
    *(float2*)&out[(size_t)(j0 + 1) * D_ + 2 * lane] = r;
    r.x = (A2.x + B2.x) * sc2; r.y = (A2.y + B2.y) * sc2;
    *(float2*)&out[(size_t)(j0 + 2) * D_ + 2 * lane] = r;
    r.x = (A3.x + B3.x) * sc3; r.y = (A3.y + B3.y) * sc3;
    *(float2*)&out[(size_t)(j0 + 3) * D_ + 2 * lane] = r;
}

// ---------- fused 2-layer MLPs, all three in one launch; 128-row tiles ----------
// (EXACT round-0 structure.) base_out != nullptr: ALSO store the pre-scale fp32
// output row (acc+bias for row 0) to base_out[seg*128 + col].
__global__ __launch_bounds__(256, 2) void mlp3_k(
    const float* __restrict__ l_cur, const float* __restrict__ c_cur,
    const unsigned short* __restrict__ wt_hi, const unsigned short* __restrict__ wt_lo,
    const float* __restrict__ bb,
    const float* __restrict__ invsq_l, const float* __restrict__ invsq_c,
    bf16* __restrict__ l_msg, bf16* __restrict__ c_msg, bf16* __restrict__ l2lb,
    int nL, int nC, float* __restrict__ base_out) {
    __shared__ char smem[66048];
    unsigned short (*a_hi)[40] = (unsigned short(*)[40])(smem);
    unsigned short (*a_lo)[40] = (unsigned short(*)[40])(smem + 10240);
    unsigned short (*b_hi)[40] = (unsigned short(*)[40])(smem + 20480);
    unsigned short (*b_lo)[40] = (unsigned short(*)[40])(smem + 30720);
    unsigned short* h_hi = (unsigned short*)(smem);          // phase 2 aliases tiles
    unsigned short* h_lo = (unsigned short*)(smem + 32768);
    float* scv = (float*)(smem + 65536);                     // 128 floats, non-aliased

    int b = blockIdx.x, seg, tile;
    if (b < nL)           { seg = 0; tile = b; }
    else if (b < nL + nC) { seg = 1; tile = b - nL; }
    else                  { seg = 2; tile = b - nL - nC; }
    const float* A = (seg == 1) ? c_cur : l_cur;
    bf16* outp = (seg == 0) ? l_msg : (seg == 1) ? c_msg : l2lb;
    const float* invsq = (seg == 0) ? invsq_l : (seg == 1) ? invsq_c : nullptr;
    const unsigned short* W1h = wt_hi + seg * 32768;
    const unsigned short* W1l = wt_lo + seg * 32768;
    const unsigned short* W2h = W1h + 16384;
    const unsigned short* W2l = W1l + 16384;
    const float* b1v = bb + seg * 256;
    const float* b2v = b1v + 128;
    const int swap = (seg == 2);

    const int t = threadIdx.x;
    const int br0 = tile * 128;
    const int w = t >> 6, lane = t & 63;
    const int wr = w >> 1, wc = w & 1;
    const int quad = lane >> 4, cl = lane & 15;

    if (t < 128) scv[t] = invsq ? invsq[br0 + t] : 1.0f;

    f32x4 acc[4][4];
#pragma unroll
    for (int i = 0; i < 4; i++)
#pragma unroll
        for (int j = 0; j < 4; j++) acc[i][j] = (f32x4){0.f, 0.f, 0.f, 0.f};

    // ---- phase 1: h = A @ W1 ----
    for (int kt = 0; kt < 128; kt += 32) {
#pragma unroll
        for (int i = 0; i < 4; i++) {
            int f = t + 256 * i;
            int r = f >> 3, kq = f & 7;
            int gr = br0 + r;
            if (swap) gr ^= 1;
            const float4 v = *(const float4*)&A[(size_t)gr * D_ + kt + 4 * kq];
            unsigned short h0, l0, h1, l1, h2, l2, h3, l3;
            split2(v.x, h0, l0); split2(v.y, h1, l1);
            split2(v.z, h2, l2); split2(v.w, h3, l3);
            *(ushort4*)&a_hi[r][4 * kq] = make_ushort4(h0, h1, h2, h3);
            *(ushort4*)&a_lo[r][4 * kq] = make_ushort4(l0, l1, l2, l3);
            *(ushort4*)&b_hi[r][4 * kq] = *(const ushort4*)&W1h[(size_t)r * 128 + kt + 4 * kq];
            *(ushort4*)&b_lo[r][4 * kq] = *(const ushort4*)&W1l[(size_t)r * 128 + kt + 4 * kq];
        }
        __syncthreads();
        short8 af_h[4], af_l[4];
#pragma unroll
        for (int i = 0; i < 4; i++) {
            int row = 64 * wr + 16 * i + cl;
            af_h[i] = *(const short8*)&a_hi[row][quad * 8];
            af_l[i] = *(const short8*)&a_lo[row][quad * 8];
        }
#pragma unroll
        for (int j = 0; j < 4; j++) {
            int col = 64 * wc + 16 * j + cl;
            short8 bf_h = *(const short8*)&b_hi[col][quad * 8];
            short8 bf_l = *(const short8*)&b_lo[col][quad * 8];
#pragma unroll
            for (int i = 0; i < 4; i++) {
                acc[i][j] = __builtin_amdgcn_mfma_f32_16x16x32_bf16(af_h[i], bf_h, acc[i][j], 0, 0, 0);
                acc[i][j] = __builtin_amdgcn_mfma_f32_16x16x32_bf16(af_h[i], bf_l, acc[i][j], 0, 0, 0);
                acc[i][j] = __builtin_amdgcn_mfma_f32_16x16x32_bf16(af_l[i], bf_h, acc[i][j], 0, 0, 0);
            }
        }
        __syncthreads();
    }
    // h epilogue: bias + relu + split -> swizzled LDS. C/D: col=cl, row=quad*4+reg.
#pragma unroll
    for (int j = 0; j < 4; j++) {
        int col = 64 * wc + 16 * j + cl;
        float bv = b1v[col];
        int g = col >> 3, go = col & 7;
#pragma unroll
        for (int i = 0; i < 4; i++) {
            int rloc = 64 * wr + 16 * i + quad * 4;
#pragma unroll
            for (int rg = 0; rg < 4; rg++) {
                float v = fmaxf(acc[i][j][rg] + bv, 0.0f);
                unsigned short hh, ll;
                split2(v, hh, ll);
                int r = rloc + rg;
                int off = r * 128 + ((g ^ (r & 15)) << 3) + go;
                h_hi[off] = hh;
                h_lo[off] = ll;
            }
        }
    }
    __syncthreads();
    // ---- phase 2: out = (h @ W2 + b2) * scv -> bf16 ----
#pragma unroll
    for (int i = 0; i < 4; i++)
#pragma unroll
        for (int j = 0; j < 4; j++) acc[i][j] = (f32x4){0.f, 0.f, 0.f, 0.f};

    for (int kt = 0; kt < 128; kt += 32) {
        short8 af_h[4], af_l[4];
        int gbase = (kt >> 3) + quad;
#pragma unroll
        for (int i = 0; i < 4; i++) {
            int r = 64 * wr + 16 * i + cl;
            int off = r * 128 + ((gbase ^ cl) << 3);
            af_h[i] = *(const short8*)&h_hi[off];
            af_l[i] = *(const short8*)&h_lo[off];
        }
#pragma unroll
        for (int j = 0; j < 4; j++) {
            int col = 64 * wc + 16 * j + cl;
            const short8 bf_h = *(const short8*)&W2h[(size_t)col * 128 + kt + quad * 8];
            const short8 bf_l = *(const short8*)&W2l[(size_t)col * 128 + kt + quad * 8];
#pragma unroll
            for (int i = 0; i < 4; i++) {
                acc[i][j] = __builtin_amdgcn_mfma_f32_16x16x32_bf16(af_h[i], bf_h, acc[i][j], 0, 0, 0);
                acc[i][j] = __builtin_amdgcn_mfma_f32_16x16x32_bf16(af_h[i], bf_l, acc[i][j], 0, 0, 0);
                acc[i][j] = __builtin_amdgcn_mfma_f32_16x16x32_bf16(af_l[i], bf_h, acc[i][j], 0, 0, 0);
            }
        }
    }
#pragma unroll
    for (int j = 0; j < 4; j++) {
        int col = 64 * wc + 16 * j + cl;
        float bv = b2v[col];
        if (base_out && w < 2 && lane < 16)
            base_out[seg * 128 + col] = acc[0][j][0] + bv;   // row 0, pre-scale fp32
#pragma unroll
        for (int i = 0; i < 4; i++) {
            int rloc = 64 * wr + 16 * i + quad * 4;
#pragma unroll
            for (int rg = 0; rg < 4; rg++)
                outp[(size_t)(br0 + rloc + rg) * D_ + col] =
                    __float2bfloat16((acc[i][j][rg] + bv) * scv[rloc + rg]);
        }
    }
}

// ---------- fused update GEMMs; 128-row tiles (EXACT round-0 body) ----------
// (256,4): 40KB LDS allows 4 independent blocks/CU (vs 2) -- anti-phase blocks
// overlap one block's staging drain with another's MFMA burst. Body unchanged.
template <int FINAL>
__global__ __launch_bounds__(256, 4) void update_k(
    const float* __restrict__ l_cur, const float* __restrict__ c_cur,
    const float* __restrict__ laggr, const float* __restrict__ caggr,
    const bf16* __restrict__ l2lb,
    const unsigned short* __restrict__ wt_hi, const unsigned short* __restrict__ wt_lo,
    const float* __restrict__ bb,
    float* __restrict__ c_nxt, float* __restrict__ l_nxt,
    void* __restrict__ dout, const int* __restrict__ flags) {
    __shared__ unsigned short a_hi[128][40], a_lo[128][40];
    __shared__ unsigned short b_hi[128][40], b_lo[128][40];
    const int t = threadIdx.x;
    int b = blockIdx.x;
    const bool cseg = (!FINAL) && (b < 256);
    const int tile = (FINAL || cseg) ? b : b - 256;
    const int K = cseg ? 256 : 384;
    const float* A0 = cseg ? c_cur : l_cur;
    const float* A1 = cseg ? caggr : laggr;
    const unsigned short* Wh = wt_hi + (cseg ? 98304 : 131072);
    const unsigned short* Wl = wt_lo + (cseg ? 98304 : 131072);
    const float* bias = bb + (cseg ? 768 : 896);
    const int br0 = tile * 128;
    const int w = t >> 6, lane = t & 63;
    const int wr = w >> 1, wc = w & 1;
    const int quad = lane >> 4, cl = lane & 15;

    f32x4 acc[4][4];
#pragma unroll
    for (int i = 0; i < 4; i++)
#pragma unroll
        for (int j = 0; j < 4; j++) acc[i][j] = (f32x4){0.f, 0.f, 0.f, 0.f};

    for (int kt = 0; kt < K; kt += 32) {
        const bool haslo = (kt < 256);
        const int koff = kt & 127;
#pragma unroll
        for (int i = 0; i < 4; i++) {
            int f = t + 256 * i;
            int r = f >> 3, kq = f & 7;
            if (haslo) {
                const float* As = (kt < 128) ? A0 : A1;
                const float4 v = *(const float4*)&As[(size_t)(br0 + r) * D_ + koff + 4 * kq];
                unsigned short h0, l0, h1, l1, h2, l2, h3, l3;
                split2(v.x, h0, l0); split2(v.y, h1, l1);
                split2(v.z, h2, l2); split2(v.w, h3, l3);
                *(ushort4*)&a_hi[r][4 * kq] = make_ushort4(h0, h1, h2, h3);
                *(ushort4*)&a_lo[r][4 * kq] = make_ushort4(l0, l1, l2, l3);
            } else {
                *(ushort4*)&a_hi[r][4 * kq] =
                    *(const ushort4*)&l2lb[(size_t)(br0 + r) * D_ + koff + 4 * kq];
            }
            *(ushort4*)&b_hi[r][4 * kq] = *(const ushort4*)&Wh[(size_t)r * K + kt + 4 * kq];
            *(ushort4*)&b_lo[r][4 * kq] = *(const ushort4*)&Wl[(size_t)r * K + kt + 4 * kq];
        }
        __syncthreads();
        short8 af_h[4], af_l[4];
#pragma unroll
        for (int i = 0; i < 4; i++) {
            int row = 64 * wr + 16 * i + cl;
            af_h[i] = *(const short8*)&a_hi[row][quad * 8];
            if (haslo) af_l[i] = *(const short8*)&a_lo[row][quad * 8];
        }
#pragma unroll
        for (int j = 0; j < 4; j++) {
            int col = 64 * wc + 16 * j + cl;
            short8 bf_h = *(const short8*)&b_hi[col][quad * 8];
            short8 bf_l = *(const short8*)&b_lo[col][quad * 8];
#pragma unroll
            for (int i = 0; i < 4; i++) {
                acc[i][j] = __builtin_amdgcn_mfma_f32_16x16x32_bf16(af_h[i], bf_h, acc[i][j], 0, 0, 0);
                acc[i][j] = __builtin_amdgcn_mfma_f32_16x16x32_bf16(af_h[i], bf_l, acc[i][j], 0, 0, 0);
                if (haslo)
                    acc[i][j] = __builtin_amdgcn_mfma_f32_16x16x32_bf16(af_l[i], bf_h, acc[i][j], 0, 0, 0);
            }
        }
        __syncthreads();
    }
    const int f32out = FINAL ? flags[0] : 1;
#pragma unroll
    for (int j = 0; j < 4; j++) {
        int col = 64 * wc + 16 * j + cl;
        float bv = bias[col];
#pragma unroll
        for (int i = 0; i < 4; i++) {
            int rbase = br0 + 64 * wr + 16 * i + quad * 4;
#pragma unroll
            for (int rg = 0; rg < 4; rg++) {
                float v = acc[i][j][rg] + bv;
                size_t idx = (size_t)(rbase + rg) * D_ + col;
                if (FINAL) {
                    if (f32out) ((float*)dout)[idx] = v;
                    else        ((bf16*)dout)[idx] = __float2bfloat16(v);
                } else {
                    (cseg ? c_nxt : l_nxt)[idx] = v;
                }
            }
        }
    }
}

extern "C" void kernel_launch(void* const* d_in, const int* in_sizes, int n_in,
                              void* d_out, int out_size, void* d_ws, size_t ws_size,
                              hipStream_t stream) {
    const int* li_raw = (const int*)d_in[0];
    const int* ci_raw = (const int*)d_in[1];

    // ---- workspace layout (flags after cdegi -> one zeroing memset) ----
    float* ws = (float*)d_ws;
    float* lbuf0 = ws;                               // L*D
    float* lbuf1 = lbuf0 + (size_t)L_ * D_;          // L*D  (doubles as bf16 l_msg)
    float* l2lb  = lbuf1 + (size_t)L_ * D_;          // L*D  (bf16 l2l messages)
    float* laggr = l2lb + (size_t)L_ * D_;           // L*D
    float* cbuf0 = laggr + (size_t)L_ * D_;          // C*D
    float* cbuf1 = cbuf0 + (size_t)C_ * D_;          // C*D  (doubles as bf16 c_msg)
    float* caggr = cbuf1 + (size_t)C_ * D_;          // C*D
    float* invsq_l = caggr + (size_t)C_ * D_;        // L
    float* invsq_c = invsq_l + L_;                   // C
    float* bb    = invsq_c + C_;                     // 1024 bias floats
    unsigned short* wt_hi = (unsigned short*)(bb + 1024);   // 180224 ushorts
    unsigned short* wt_lo = wt_hi + 180224;                 // 180224 ushorts
    int*   li    = (int*)(wt_lo + 180224);           // E
    int*   ci    = li + E_;                          // E
    int*   l_other = ci + E_;                        // E
    int*   c_other = l_other + E_;                   // E
    int*   ldegi = c_other + E_;                     // L
    int*   cdegi = ldegi + L_;                       // C
    int*   flags = cdegi + C_;                       // 2  (contiguous with deg arrays)
    int*   lptr  = flags + 2;                        // L
    int*   cptr  = lptr + L_;                        // C
    int*   lcur  = cptr + C_;                        // L
    int*   ccur  = lcur + L_;                        // C
    int*   bsumL = ccur + C_;                        // 256
    int*   bsumC = bsumL + 256;                      // 128
    float* baseb = (float*)(bsumC + 128);            // 384 fp32 (it=0 MLP base rows)
    float* ucbuf = baseb + 384;                      // 384 fp32 (it=0 update consts)

    // --- one memset zeroes degrees + flags; then dtype detection ---
    hipMemsetAsync(ldegi, 0, ((size_t)(L_ + C_) + 2) * sizeof(int), stream);
    detect_k<<<16, 512, 0, stream>>>((const unsigned short*)d_in[4], li_raw, flags);

    // --- fused preamble: fixdeg + weight-split + tile-0 embedding-init ---
    prep_k<<<2788, 256, 0, stream>>>(
        li_raw, ci_raw, li, ci, ldegi, cdegi,
        d_in[4], d_in[6], d_in[8], d_in[10], d_in[12], d_in[14], d_in[16], d_in[18],
        d_in[5], d_in[7], d_in[9], d_in[11], d_in[13], d_in[15], d_in[17], d_in[19],
        wt_hi, wt_lo, bb,
        d_in[2], d_in[3], lbuf0, cbuf0, flags);

    // --- CSR build ---
    scan1b_k<<<384, 256, 0, stream>>>(ldegi, cdegi, lptr, cptr, bsumL, bsumC);
    scan3b_k<<<384, 256, 0, stream>>>(lptr, cptr, bsumL, bsumC, lcur, ccur,
                                      ldegi, cdegi, invsq_l, invsq_c);
    place_k<<<E_ / 256, 256, 0, stream>>>(li, ci, lcur, ccur, l_other, c_other);

    float* l_cur = lbuf0; float* l_nxt = lbuf1;
    float* c_cur = cbuf0; float* c_nxt = cbuf1;

    const int nL = L_ / 128, nC = C_ / 128;

    // ---- it=0: degenerate (row-uniform embeddings) fast path ----
    mlp3_k<<<3, 256, 0, stream>>>(
        l_cur, c_cur, wt_hi, wt_lo, bb, invsq_l, invsq_c,
        (bf16*)l_nxt, (bf16*)c_nxt, (bf16*)l2lb, 1, 1, baseb);
    bcast_k<<<8, 256, 0, stream>>>(baseb, (bf16*)l2lb);
    uconst_k<<<2, 256, 0, stream>>>(
        l_cur, c_cur, (const bf16*)l2lb, wt_hi, wt_lo, ucbuf);
    gather0_k<<<(C_ + L_) / 16, 256, 0, stream>>>(
        cptr, cdegi, c_other, baseb, invsq_l, invsq_c, caggr,
        lptr, ldegi, l_other, laggr, C_);
    update0_k<<<768, 256, 0, stream>>>(
        laggr, caggr, wt_hi, wt_lo, bb, ucbuf, c_nxt, l_nxt);
    { float* tmp = l_cur; l_cur = l_nxt; l_nxt = tmp;
      tmp = c_cur; c_cur = c_nxt; c_nxt = tmp; }

    // ---- it=1,2: full pipeline ----
    for (int it = 1; it < 3; it++) {
        mlp3_k<<<2 * nL + nC, 256, 0, stream>>>(
            l_cur, c_cur, wt_hi, wt_lo, bb, invsq_l, invsq_c,
            (bf16*)l_nxt, (bf16*)c_nxt, (bf16*)l2lb, nL, nC, nullptr);
        gather2_k<<<(C_ + L_) / 16, 256, 0, stream>>>(
            cptr, cdegi, c_other, (const unsigned int*)l_nxt, invsq_c, caggr,
            lptr, ldegi, l_other, (const unsigned int*)c_nxt, invsq_l, laggr, C_);
        update_k<0><<<768, 256, 0, stream>>>(
            l_cur, c_cur, laggr, caggr, (const bf16*)l2lb, wt_hi, wt_lo, bb,
            c_nxt, l_nxt, nullptr, flags);
        float* tmp = l_cur; l_cur = l_nxt; l_nxt = tmp;
        tmp = c_cur; c_cur = c_nxt; c_nxt = tmp;
    }
    // --- final iteration: c-update dead -> skip l2c MLP, c-gather, c-update;
    //     fuse output dtype conversion into the l-update epilogue ---
    mlp3_k<<<nC + nL, 256, 0, stream>>>(
        l_cur, c_cur, wt_hi, wt_lo, bb, invsq_l, invsq_c,
        (bf16*)l_nxt, (bf16*)c_nxt, (bf16*)l2lb, 0, nC, nullptr);
    gather2_k<<<L_ / 16, 256, 0, stream>>>(
        cptr, cdegi, c_other, (const unsigned int*)l_nxt, invsq_c, caggr,
        lptr, ldegi, l_other, (const unsigned int*)c_nxt, invsq_l, laggr, 0);
    update_k<1><<<512, 256, 0, stream>>>(
        l_cur, c_cur, laggr, caggr, (const bf16*)l2lb, wt_hi, wt_lo, bb,
        nullptr, nullptr, d_out, flags);
}

// Round 16
// 595.727 us; speedup vs baseline: 1.1435x; 1.1435x over previous
//
#include <hip/hip_runtime.h>
#include <hip/hip_bf16.h>

#define D_ 128
#define L_ 65536
#define C_ 32768
#define E_ 262144

typedef __hip_bfloat16 bf16;
typedef __attribute__((ext_vector_type(8))) short short8;
typedef __attribute__((ext_vector_type(4))) float f32x4;

// flags[0] = 1 if float inputs are fp32 (else bf16); flags[1] = 1 if edge idx int32 (else int64)
__global__ void detect_k(const unsigned short* __restrict__ wmem,
                         const int* __restrict__ li, int* __restrict__ flags) {
    int t = blockIdx.x * 512 + threadIdx.x;
    if (t < 8192) {
        unsigned short h = wmem[2 * t];
        float v = __bfloat162float(*(const bf16*)&h);
        if (!(fabsf(v) < 0.5f)) atomicOr(&flags[0], 1);
    }
    if (t < 2048) {
        if (li[2 * t + 1] != 0) atomicOr(&flags[1], 1);
    }
}

__device__ __forceinline__ void split2(float v, unsigned short& h, unsigned short& l) {
    bf16 bh = __float2bfloat16(v);
    float fh = __bfloat162float(bh);
    bf16 bl = __float2bfloat16(v - fh);
    h = *(unsigned short*)&bh;
    l = *(unsigned short*)&bl;
}

__device__ __forceinline__ float ldf(const void* s, int i, int isf32) {
    return isf32 ? ((const float*)s)[i] : __bfloat162float(((const bf16*)s)[i]);
}

// ---- fused preamble: fixdeg (2048 blocks) + cvtwb (708) + tile-0 init2 (32) ----
__global__ void prep_k(const int* __restrict__ ls, const int* __restrict__ cs,
                       int* __restrict__ ld_idx, int* __restrict__ cd_idx,
                       int* __restrict__ ldeg, int* __restrict__ cdeg,
                       const void* s0, const void* s1, const void* s2, const void* s3,
                       const void* s4, const void* s5, const void* s6, const void* s7,
                       const void* t0, const void* t1, const void* t2, const void* t3,
                       const void* t4, const void* t5, const void* t6, const void* t7,
                       unsigned short* __restrict__ hi, unsigned short* __restrict__ lo,
                       float* __restrict__ bb,
                       const void* __restrict__ lv, const void* __restrict__ cv,
                       float* __restrict__ lemb, float* __restrict__ cemb,
                       const int* __restrict__ flags) {
    const int blk = blockIdx.x;
    const int isf = flags[0];
    if (blk < 2048) {
        int i = blk * 256 + threadIdx.x;
        int is32 = flags[1];
        if (i < E_) {
            int v = is32 ? ls[i] : ls[2 * i];
            v = min(max(v, 0), L_ - 1);
            ld_idx[i] = v;
            atomicAdd(&ldeg[v], 1);
        } else {
            int j = i - E_;
            int v = is32 ? cs[j] : cs[2 * j];
            v = min(max(v, 0), C_ - 1);
            cd_idx[j] = v;
            atomicAdd(&cdeg[v], 1);
        }
        return;
    }
    if (blk < 2756) {
        int i = (blk - 2048) * 256 + threadIdx.x;  // 181248 total
        if (i >= 180224) {
            int j = i - 180224;  // 0..1023
            const void* src;
            switch (j >> 7) {
                case 0: src = t0; break; case 1: src = t1; break;
                case 2: src = t2; break; case 3: src = t3; break;
                case 4: src = t4; break; case 5: src = t5; break;
                case 6: src = t6; break; default: src = t7; break;
            }
            bb[j] = ldf(src, j & 127, isf);
            return;
        }
        const void* src; int K, base;
        if      (i <  16384) { src = s0; K = 128; base = 0; }
        else if (i <  32768) { src = s1; K = 128; base = 16384; }
        else if (i <  49152) { src = s2; K = 128; base = 32768; }
        else if (i <  65536) { src = s3; K = 128; base = 49152; }
        else if (i <  81920) { src = s4; K = 128; base = 65536; }
        else if (i <  98304) { src = s5; K = 128; base = 81920; }
        else if (i < 131072) { src = s6; K = 256; base = 98304; }
        else                 { src = s7; K = 384; base = 131072; }
        int e = i - base;
        int k = e >> 7, n = e & 127;
        float v = ldf(src, e, isf);
        unsigned short h, l;
        split2(v, h, l);
        hi[base + n * K + k] = h;
        lo[base + n * K + k] = l;
        return;
    }
    // ---- init2 (tile 0 only): blocks [2756, 2788) -> 8192 float4 writes ----
    int i4 = (blk - 2756) * 256 + threadIdx.x;  // 0..8191
    const void* src; float* dst; int o;
    if (i4 < 4096) { src = lv; dst = lemb; o = i4; }       // l rows 0..127
    else           { src = cv; dst = cemb; o = i4 - 4096; } // c rows 0..127
    int j = (o & 31) * 4;
    float4 v;
    v.x = ldf(src, j + 0, isf);
    v.y = ldf(src, j + 1, isf);
    v.z = ldf(src, j + 2, isf);
    v.w = ldf(src, j + 3, isf);
    ((float4*)dst)[o] = v;
}

// --- per-tile exclusive scan (stage 1), both sides fused ---
__global__ void scan1b_k(const int* __restrict__ ldeg, const int* __restrict__ cdeg,
                         int* __restrict__ lout, int* __restrict__ cout,
                         int* __restrict__ bsumL, int* __restrict__ bsumC) {
    __shared__ int s[256];
    const int* in; int* out; int* bs; int tile;
    if (blockIdx.x < 256) { in = ldeg; out = lout; bs = bsumL; tile = blockIdx.x; }
    else                  { in = cdeg; out = cout; bs = bsumC; tile = blockIdx.x - 256; }
    int i = tile * 256 + threadIdx.x;
    int v = in[i];
    s[threadIdx.x] = v;
    __syncthreads();
#pragma unroll
    for (int off = 1; off < 256; off <<= 1) {
        int t = (threadIdx.x >= off) ? s[threadIdx.x - off] : 0;
        __syncthreads();
        s[threadIdx.x] += t;
        __syncthreads();
    }
    out[i] = s[threadIdx.x] - v;
    if (threadIdx.x == 255) bs[tile] = s[255];
}

// stage 2+3 fused: each block redundantly computes its own bsum prefix.
__global__ void scan3b_k(int* __restrict__ lptr, int* __restrict__ cptr,
                         const int* __restrict__ bsumL, const int* __restrict__ bsumC,
                         int* __restrict__ lcur, int* __restrict__ ccur,
                         const int* __restrict__ ldeg, const int* __restrict__ cdeg,
                         float* __restrict__ invsq_l, float* __restrict__ invsq_c) {
    __shared__ int sh[256];
    int b = blockIdx.x, t = threadIdx.x;
    const bool lside = (b < 256);
    const int tile = lside ? b : b - 256;
    const int* bs = lside ? bsumL : bsumC;
    sh[t] = (t < tile) ? bs[t] : 0;
    __syncthreads();
#pragma unroll
    for (int off = 128; off > 0; off >>= 1) {
        if (t < off) sh[t] += sh[t + off];
        __syncthreads();
    }
    const int pref = sh[0];
    int i = tile * 256 + t;
    if (lside) {
        int v = lptr[i] + pref;
        lptr[i] = v; lcur[i] = v;
        int d = ldeg[i];
        invsq_l[i] = d ? rsqrtf((float)d) : 0.0f;
    } else {
        int v = cptr[i] + pref;
        cptr[i] = v; ccur[i] = v;
        int d = cdeg[i];
        invsq_c[i] = d ? rsqrtf((float)d) : 0.0f;
    }
}

// CSR placement (other endpoint only; norm is separable)
__global__ void place_k(const int* __restrict__ li, const int* __restrict__ ci,
                        int* __restrict__ lcur, int* __restrict__ ccur,
                        int* __restrict__ l_other, int* __restrict__ c_other) {
    int e = blockIdx.x * 256 + threadIdx.x;
    if (e >= E_) return;
    int l = li[e], c = ci[e];
    int p = atomicAdd(&ccur[c], 1);
    c_other[p] = l;
    int q = atomicAdd(&lcur[l], 1);
    l_other[q] = c;
}

// it=0: l2l rows 0..127 only (sole reader is uconst_k pass 2). 8 blocks.
__global__ void bcast_k(const float* __restrict__ baseb, bf16* __restrict__ l2lb) {
    int id = blockIdx.x * 256 + threadIdx.x;   // 2048 ids, each writes 8 bf16
    const float* base = baseb + 256;
    int row = id >> 4, c8 = (id & 15) * 8;
    union { short8 v; unsigned short u[8]; } o;
#pragma unroll
    for (int k = 0; k < 8; k++) {
        bf16 b = __float2bfloat16(base[c8 + k]);
        o.u[k] = *(unsigned short*)&b;
    }
    *(short8*)&l2lb[(size_t)row * D_ + c8] = o.v;
}

// it=0 gather: messages are rank-1 (msg[o][col] = bf16(base[col]*invsq_src[o])),
// so synthesize them in-register: per edge load only invsq_src[o] (4B broadcast)
// instead of a 256B scattered message row. Accumulation structure/order is
// IDENTICAL to gather2_k (same 4-node 2-deep pairing, same tails) and the
// synthesized values are bitwise identical to what bcast would have written.
__global__ __launch_bounds__(256) void gather0_k(
    const int* __restrict__ cptr, const int* __restrict__ cdeg, const int* __restrict__ c_other,
    const float* __restrict__ baseb,
    const float* __restrict__ invsq_l, const float* __restrict__ invsq_c,
    float* __restrict__ caggr,
    const int* __restrict__ lptr, const int* __restrict__ ldeg, const int* __restrict__ l_other,
    float* __restrict__ laggr, int nC) {
    int wid = (blockIdx.x * 256 + threadIdx.x) >> 6;
    int lane = threadIdx.x & 63;
    int n0 = 4 * wid;
    bool cside = n0 < nC;
    int j0 = cside ? n0 : n0 - nC;
    const int* ptr = cside ? cptr : lptr;
    const int* dg  = cside ? cdeg : ldeg;
    const int* oth = cside ? c_other : l_other;
    const float* isrc = cside ? invsq_l : invsq_c;      // SOURCE-side scale
    const float* invsq = cside ? invsq_c : invsq_l;     // dest-side scale
    const float* base = baseb + (cside ? 0 : 128);      // l2c base / c2l base
    float* out = cside ? caggr : laggr;
    const float b0 = base[2 * lane], b1 = base[2 * lane + 1];

    int s0 = ptr[j0],     c0 = dg[j0];
    int s1 = ptr[j0 + 1], c1 = dg[j0 + 1];
    int s2 = ptr[j0 + 2], c2 = dg[j0 + 2];
    int s3 = ptr[j0 + 3], c3 = dg[j0 + 3];
    float2 A0 = {0.f, 0.f}, B0 = {0.f, 0.f};
    float2 A1 = {0.f, 0.f}, B1 = {0.f, 0.f};
    float2 A2 = {0.f, 0.f}, B2 = {0.f, 0.f};
    float2 A3 = {0.f, 0.f}, B3 = {0.f, 0.f};
    int k0 = 0, k1 = 0, k2 = 0, k3 = 0;

#define GSC_(s, k) isrc[oth[(s) + (k)]]
#define GACCs_(a, sc) { (a).x += __bfloat162float(__float2bfloat16(b0 * (sc))); \
                        (a).y += __bfloat162float(__float2bfloat16(b1 * (sc))); }

    for (; k0 + 2 <= c0 && k1 + 2 <= c1 && k2 + 2 <= c2 && k3 + 2 <= c3;
         k0 += 2, k1 += 2, k2 += 2, k3 += 2) {
        float sc00 = GSC_(s0, k0), sc01 = GSC_(s0, k0 + 1);
        float sc10 = GSC_(s1, k1), sc11 = GSC_(s1, k1 + 1);
        float sc20 = GSC_(s2, k2), sc21 = GSC_(s2, k2 + 1);
        float sc30 = GSC_(s3, k3), sc31 = GSC_(s3, k3 + 1);
        GACCs_(A0, sc00); GACCs_(B0, sc01);
        GACCs_(A1, sc10); GACCs_(B1, sc11);
        GACCs_(A2, sc20); GACCs_(B2, sc21);
        GACCs_(A3, sc30); GACCs_(B3, sc31);
    }
    for (; k0 + 2 <= c0 && k1 + 2 <= c1; k0 += 2, k1 += 2) {
        float sc00 = GSC_(s0, k0), sc01 = GSC_(s0, k0 + 1);
        float sc10 = GSC_(s1, k1), sc11 = GSC_(s1, k1 + 1);
        GACCs_(A0, sc00); GACCs_(B0, sc01);
        GACCs_(A1, sc10); GACCs_(B1, sc11);
    }
    for (; k2 + 2 <= c2 && k3 + 2 <= c3; k2 += 2, k3 += 2) {
        float sc20 = GSC_(s2, k2), sc21 = GSC_(s2, k2 + 1);
        float sc30 = GSC_(s3, k3), sc31 = GSC_(s3, k3 + 1);
        GACCs_(A2, sc20); GACCs_(B2, sc21);
        GACCs_(A3, sc30); GACCs_(B3, sc31);
    }
    for (; k0 + 2 <= c0; k0 += 2) {
        float sa = GSC_(s0, k0), sb = GSC_(s0, k0 + 1);
        GACCs_(A0, sa); GACCs_(B0, sb);
    }
    for (; k1 + 2 <= c1; k1 += 2) {
        float sa = GSC_(s1, k1), sb = GSC_(s1, k1 + 1);
        GACCs_(A1, sa); GACCs_(B1, sb);
    }
    for (; k2 + 2 <= c2; k2 += 2) {
        float sa = GSC_(s2, k2), sb = GSC_(s2, k2 + 1);
        GACCs_(A2, sa); GACCs_(B2, sb);
    }
    for (; k3 + 2 <= c3; k3 += 2) {
        float sa = GSC_(s3, k3), sb = GSC_(s3, k3 + 1);
        GACCs_(A3, sa); GACCs_(B3, sb);
    }
    if (k0 < c0) { float sa = GSC_(s0, k0); GACCs_(A0, sa); }
    if (k1 < c1) { float sa = GSC_(s1, k1); GACCs_(A1, sa); }
    if (k2 < c2) { float sa = GSC_(s2, k2); GACCs_(A2, sa); }
    if (k3 < c3) { float sa = GSC_(s3, k3); GACCs_(A3, sa); }
#undef GSC_
#undef GACCs_

    float sc0 = invsq[j0], sc1 = invsq[j0 + 1];
    float sc2 = invsq[j0 + 2], sc3 = invsq[j0 + 3];
    float2 r;
    r.x = (A0.x + B0.x) * sc0; r.y = (A0.y + B0.y) * sc0;
    *(float2*)&out[(size_t)j0 * D_ + 2 * lane] = r;
    r.x = (A1.x + B1.x) * sc1; r.y = (A1.y + B1.y) * sc1;
    *(float2*)&out[(size_t)(j0 + 1) * D_ + 2 * lane] = r;
    r.x = (A2.x + B2.x) * sc2; r.y = (A2.y + B2.y) * sc2;
    *(float2*)&out[(size_t)(j0 + 2) * D_ + 2 * lane] = r;
    r.x = (A3.x + B3.x) * sc3; r.y = (A3.y + B3.y) * sc3;
    *(float2*)&out[(size_t)(j0 + 3) * D_ + 2 * lane] = r;
}

// it=0 uniform-range constants for update (runs EXACT update_k staging+MFMA
// sequence on tile 0 for the row-uniform K ranges; stores row 0's acc).
__global__ __launch_bounds__(256, 2) void uconst_k(
    const float* __restrict__ l_cur, const float* __restrict__ c_cur,
    const bf16* __restrict__ l2lb,
    const unsigned short* __restrict__ wt_hi, const unsigned short* __restrict__ wt_lo,
    float* __restrict__ uc) {
    __shared__ unsigned short a_hi[128][40], a_lo[128][40];
    __shared__ unsigned short b_hi[128][40], b_lo[128][40];
    const int t = threadIdx.x;
    const bool cseg = (blockIdx.x == 0);
    const int K = cseg ? 256 : 384;
    const float* A0 = cseg ? c_cur : l_cur;
    const unsigned short* Wh = wt_hi + (cseg ? 98304 : 131072);
    const unsigned short* Wl = wt_lo + (cseg ? 98304 : 131072);
    const int w = t >> 6, lane = t & 63;
    const int wr = w >> 1, wc = w & 1;
    const int quad = lane >> 4, cl = lane & 15;

    f32x4 acc[4][4];
#pragma unroll
    for (int i = 0; i < 4; i++)
#pragma unroll
        for (int j = 0; j < 4; j++) acc[i][j] = (f32x4){0.f, 0.f, 0.f, 0.f};

    for (int kt = 0; kt < 128; kt += 32) {
#pragma unroll
        for (int i = 0; i < 4; i++) {
            int f = t + 256 * i;
            int r = f >> 3, kq = f & 7;
            const float4 v = *(const float4*)&A0[(size_t)r * D_ + kt + 4 * kq];
            unsigned short h0, l0, h1, l1, h2, l2, h3, l3;
            split2(v.x, h0, l0); split2(v.y, h1, l1);
            split2(v.z, h2, l2); split2(v.w, h3, l3);
            *(ushort4*)&a_hi[r][4 * kq] = make_ushort4(h0, h1, h2, h3);
            *(ushort4*)&a_lo[r][4 * kq] = make_ushort4(l0, l1, l2, l3);
            *(ushort4*)&b_hi[r][4 * kq] = *(const ushort4*)&Wh[(size_t)r * K + kt + 4 * kq];
            *(ushort4*)&b_lo[r][4 * kq] = *(const ushort4*)&Wl[(size_t)r * K + kt + 4 * kq];
        }
        __syncthreads();
        short8 af_h[4], af_l[4];
#pragma unroll
        for (int i = 0; i < 4; i++) {
            int row = 64 * wr + 16 * i + cl;
            af_h[i] = *(const short8*)&a_hi[row][quad * 8];
            af_l[i] = *(const short8*)&a_lo[row][quad * 8];
        }
#pragma unroll
        for (int j = 0; j < 4; j++) {
            int col = 64 * wc + 16 * j + cl;
            short8 bf_h = *(const short8*)&b_hi[col][quad * 8];
            short8 bf_l = *(const short8*)&b_lo[col][quad * 8];
#pragma unroll
            for (int i = 0; i < 4; i++) {
                acc[i][j] = __builtin_amdgcn_mfma_f32_16x16x32_bf16(af_h[i], bf_h, acc[i][j], 0, 0, 0);
                acc[i][j] = __builtin_amdgcn_mfma_f32_16x16x32_bf16(af_h[i], bf_l, acc[i][j], 0, 0, 0);
                acc[i][j] = __builtin_amdgcn_mfma_f32_16x16x32_bf16(af_l[i], bf_h, acc[i][j], 0, 0, 0);
            }
        }
        __syncthreads();
    }
#pragma unroll
    for (int j = 0; j < 4; j++) {
        int col = 64 * wc + 16 * j + cl;
        if (w < 2 && lane < 16) uc[(cseg ? 0 : 128) + col] = acc[0][j][0];
    }
    if (cseg) return;

    // pass 2: l2l tiles kt=256..383 accumulated from zero (bf16 hi-plane only)
#pragma unroll
    for (int i = 0; i < 4; i++)
#pragma unroll
        for (int j = 0; j < 4; j++) acc[i][j] = (f32x4){0.f, 0.f, 0.f, 0.f};
    for (int kt = 256; kt < 384; kt += 32) {
        const int koff = kt & 127;
#pragma unroll
        for (int i = 0; i < 4; i++) {
            int f = t + 256 * i;
            int r = f >> 3, kq = f & 7;
            *(ushort4*)&a_hi[r][4 * kq] =
                *(const ushort4*)&l2lb[(size_t)r * D_ + koff + 4 * kq];
            *(ushort4*)&b_hi[r][4 * kq] = *(const ushort4*)&Wh[(size_t)r * K + kt + 4 * kq];
            *(ushort4*)&b_lo[r][4 * kq] = *(const ushort4*)&Wl[(size_t)r * K + kt + 4 * kq];
        }
        __syncthreads();
        short8 af_h[4];
#pragma unroll
        for (int i = 0; i < 4; i++) {
            int row = 64 * wr + 16 * i + cl;
            af_h[i] = *(const short8*)&a_hi[row][quad * 8];
        }
#pragma unroll
        for (int j = 0; j < 4; j++) {
            int col = 64 * wc + 16 * j + cl;
            short8 bf_h = *(const short8*)&b_hi[col][quad * 8];
            short8 bf_l = *(const short8*)&b_lo[col][quad * 8];
#pragma unroll
            for (int i = 0; i < 4; i++) {
                acc[i][j] = __builtin_amdgcn_mfma_f32_16x16x32_bf16(af_h[i], bf_h, acc[i][j], 0, 0, 0);
                acc[i][j] = __builtin_amdgcn_mfma_f32_16x16x32_bf16(af_h[i], bf_l, acc[i][j], 0, 0, 0);
            }
        }
        __syncthreads();
    }
#pragma unroll
    for (int j = 0; j < 4; j++) {
        int col = 64 * wc + 16 * j + cl;
        if (w < 2 && lane < 16) uc[256 + col] = acc[0][j][0];
    }
}

// it=0 update: acc from uniform-range constants; only the 4 aggregate K-tiles.
__global__ __launch_bounds__(256, 2) void update0_k(
    const float* __restrict__ laggr, const float* __restrict__ caggr,
    const unsigned short* __restrict__ wt_hi, const unsigned short* __restrict__ wt_lo,
    const float* __restrict__ bb, const float* __restrict__ uc,
    float* __restrict__ c_nxt, float* __restrict__ l_nxt) {
    __shared__ unsigned short a_hi[128][40], a_lo[128][40];
    __shared__ unsigned short b_hi[128][40], b_lo[128][40];
    const int t = threadIdx.x;
    int b = blockIdx.x;
    const bool cseg = (b < 256);
    const int tile = cseg ? b : b - 256;
    const int K = cseg ? 256 : 384;
    const float* A1 = cseg ? caggr : laggr;
    const unsigned short* Wh = wt_hi + (cseg ? 98304 : 131072);
    const unsigned short* Wl = wt_lo + (cseg ? 98304 : 131072);
    const float* bias = bb + (cseg ? 768 : 896);
    const float* uc0 = uc + (cseg ? 0 : 128);
    const int br0 = tile * 128;
    const int w = t >> 6, lane = t & 63;
    const int wr = w >> 1, wc = w & 1;
    const int quad = lane >> 4, cl = lane & 15;

    f32x4 acc[4][4];
#pragma unroll
    for (int j = 0; j < 4; j++) {
        int col = 64 * wc + 16 * j + cl;
        float cv = uc0[col];
#pragma unroll
        for (int i = 0; i < 4; i++) acc[i][j] = (f32x4){cv, cv, cv, cv};
    }

    for (int kt = 128; kt < 256; kt += 32) {
        const int koff = kt & 127;
#pragma unroll
        for (int i = 0; i < 4; i++) {
            int f = t + 256 * i;
            int r = f >> 3, kq = f & 7;
            const float4 v = *(const float4*)&A1[(size_t)(br0 + r) * D_ + koff + 4 * kq];
            unsigned short h0, l0, h1, l1, h2, l2, h3, l3;
            split2(v.x, h0, l0); split2(v.y, h1, l1);
            split2(v.z, h2, l2); split2(v.w, h3, l3);
            *(ushort4*)&a_hi[r][4 * kq] = make_ushort4(h0, h1, h2, h3);
            *(ushort4*)&a_lo[r][4 * kq] = make_ushort4(l0, l1, l2, l3);
            *(ushort4*)&b_hi[r][4 * kq] = *(const ushort4*)&Wh[(size_t)r * K + kt + 4 * kq];
            *(ushort4*)&b_lo[r][4 * kq] = *(const ushort4*)&Wl[(size_t)r * K + kt + 4 * kq];
        }
        __syncthreads();
        short8 af_h[4], af_l[4];
#pragma unroll
        for (int i = 0; i < 4; i++) {
            int row = 64 * wr + 16 * i + cl;
            af_h[i] = *(const short8*)&a_hi[row][quad * 8];
            af_l[i] = *(const short8*)&a_lo[row][quad * 8];
        }
#pragma unroll
        for (int j = 0; j < 4; j++) {
            int col = 64 * wc + 16 * j + cl;
            short8 bf_h = *(const short8*)&b_hi[col][quad * 8];
            short8 bf_l = *(const short8*)&b_lo[col][quad * 8];
#pragma unroll
            for (int i = 0; i < 4; i++) {
                acc[i][j] = __builtin_amdgcn_mfma_f32_16x16x32_bf16(af_h[i], bf_h, acc[i][j], 0, 0, 0);
                acc[i][j] = __builtin_amdgcn_mfma_f32_16x16x32_bf16(af_h[i], bf_l, acc[i][j], 0, 0, 0);
                acc[i][j] = __builtin_amdgcn_mfma_f32_16x16x32_bf16(af_l[i], bf_h, acc[i][j], 0, 0, 0);
            }
        }
        __syncthreads();
    }
    float* outp = cseg ? c_nxt : l_nxt;
#pragma unroll
    for (int j = 0; j < 4; j++) {
        int col = 64 * wc + 16 * j + cl;
        float bv = bias[col];
        float l2lc = cseg ? 0.0f : uc[256 + col];
#pragma unroll
        for (int i = 0; i < 4; i++) {
            int rbase = br0 + 64 * wr + 16 * i + quad * 4;
#pragma unroll
            for (int rg = 0; rg < 4; rg++) {
                float v = (acc[i][j][rg] + l2lc) + bv;
                outp[(size_t)(rbase + rg) * D_ + col] = v;
            }
        }
    }
}

// Fused pull-aggregation, both directions (r9 4-node/2-deep structure, kept).
__global__ __launch_bounds__(256) void gather2_k(
    const int* __restrict__ cptr, const int* __restrict__ cdeg, const int* __restrict__ c_other,
    const unsigned int* __restrict__ lmsg, const float* __restrict__ invsq_c, float* __restrict__ caggr,
    const int* __restrict__ lptr, const int* __restrict__ ldeg, const int* __restrict__ l_other,
    const unsigned int* __restrict__ cmsg, const float* __restrict__ invsq_l, float* __restrict__ laggr,
    int nC) {
    int wid = (blockIdx.x * 256 + threadIdx.x) >> 6;
    int lane = threadIdx.x & 63;
    int n0 = 4 * wid;
    bool cside = n0 < nC;
    int j0 = cside ? n0 : n0 - nC;
    const int* ptr = cside ? cptr : lptr;
    const int* dg  = cside ? cdeg : ldeg;
    const int* oth = cside ? c_other : l_other;
    const unsigned int* msg = cside ? lmsg : cmsg;
    const float* invsq = cside ? invsq_c : invsq_l;
    float* out = cside ? caggr : laggr;

    int s0 = ptr[j0],     c0 = dg[j0];
    int s1 = ptr[j0 + 1], c1 = dg[j0 + 1];
    int s2 = ptr[j0 + 2], c2 = dg[j0 + 2];
    int s3 = ptr[j0 + 3], c3 = dg[j0 + 3];
    float2 A0 = {0.f, 0.f}, B0 = {0.f, 0.f};
    float2 A1 = {0.f, 0.f}, B1 = {0.f, 0.f};
    float2 A2 = {0.f, 0.f}, B2 = {0.f, 0.f};
    float2 A3 = {0.f, 0.f}, B3 = {0.f, 0.f};
    int k0 = 0, k1 = 0, k2 = 0, k3 = 0;

#define GLD_(s, k) msg[(size_t)oth[(s) + (k)] * 64 + lane]
#define GACC_(a, u) { (a).x += __uint_as_float((u) << 16); \
                      (a).y += __uint_as_float((u) & 0xffff0000u); }

    for (; k0 + 2 <= c0 && k1 + 2 <= c1 && k2 + 2 <= c2 && k3 + 2 <= c3;
         k0 += 2, k1 += 2, k2 += 2, k3 += 2) {
        unsigned int u00 = GLD_(s0, k0), u01 = GLD_(s0, k0 + 1);
        unsigned int u10 = GLD_(s1, k1), u11 = GLD_(s1, k1 + 1);
        unsigned int u20 = GLD_(s2, k2), u21 = GLD_(s2, k2 + 1);
        unsigned int u30 = GLD_(s3, k3), u31 = GLD_(s3, k3 + 1);
        GACC_(A0, u00); GACC_(B0, u01);
        GACC_(A1, u10); GACC_(B1, u11);
        GACC_(A2, u20); GACC_(B2, u21);
        GACC_(A3, u30); GACC_(B3, u31);
    }
    for (; k0 + 2 <= c0 && k1 + 2 <= c1; k0 += 2, k1 += 2) {
        unsigned int u00 = GLD_(s0, k0), u01 = GLD_(s0, k0 + 1);
        unsigned int u10 = GLD_(s1, k1), u11 = GLD_(s1, k1 + 1);
        GACC_(A0, u00); GACC_(B0, u01);
        GACC_(A1, u10); GACC_(B1, u11);
    }
    for (; k2 + 2 <= c2 && k3 + 2 <= c3; k2 += 2, k3 += 2) {
        unsigned int u20 = GLD_(s2, k2), u21 = GLD_(s2, k2 + 1);
        unsigned int u30 = GLD_(s3, k3), u31 = GLD_(s3, k3 + 1);
        GACC_(A2, u20); GACC_(B2, u21);
        GACC_(A3, u30); GACC_(B3, u31);
    }
    for (; k0 + 2 <= c0; k0 += 2) {
        unsigned int ua = GLD_(s0, k0), ub = GLD_(s0, k0 + 1);
        GACC_(A0, ua); GACC_(B0, ub);
    }
    for (; k1 + 2 <= c1; k1 += 2) {
        unsigned int ua = GLD_(s1, k1), ub = GLD_(s1, k1 + 1);
        GACC_(A1, ua); GACC_(B1, ub);
    }
    for (; k2 + 2 <= c2; k2 += 2) {
        unsigned int ua = GLD_(s2, k2), ub = GLD_(s2, k2 + 1);
        GACC_(A2, ua); GACC_(B2, ub);
    }
    for (; k3 + 2 <= c3; k3 += 2) {
        unsigned int ua = GLD_(s3, k3), ub = GLD_(s3, k3 + 1);
        GACC_(A3, ua); GACC_(B3, ub);
    }
    if (k0 < c0) { unsigned int u = GLD_(s0, k0); GACC_(A0, u); }
    if (k1 < c1) { unsigned int u = GLD_(s1, k1); GACC_(A1, u); }
    if (k2 < c2) { unsigned int u = GLD_(s2, k2); GACC_(A2, u); }
    if (k3 < c3) { unsigned int u = GLD_(s3, k3); GACC_(A3, u); }
#undef GLD_
#undef GACC_

    float sc0 = invsq[j0], sc1 = invsq[j0 + 1];
    float sc2 = invsq[j0 + 2], sc3 = invsq[j0 + 3];
    float2 r;
    r.x = (A0.x + B0.x) * sc0; r.y = (A0.y + B0.y) * sc0;
    *(float2*)&out[(size_t)j0 * D_ + 2 * lane] = r;
    r.x = (A1.x + B1.x) * sc1; r.y = (A1.y + B1.y) * sc1;
    *(float2*)&out[(size_t)(j0 + 1) * D_ + 2 * lane] = r;
    r.x = (A2.x + B2.x) * sc2; r.y = (A2.y + B2.y) * sc2;
    *(float2*)&out[(size_t)(j0 + 2) * D_ + 2 * lane] = r;
    r.x = (A3.x + B3.x) * sc3; r.y = (A3.y + B3.y) * sc3;
    *(float2*)&out[(size_t)(j0 + 3) * D_ + 2 * lane] = r;
}

// ---------- fused 2-layer MLPs, all three in one launch; 128-row tiles ----------
// (EXACT round-0 structure.) base_out != nullptr: ALSO store the pre-scale fp32
// output row (acc+bias for row 0) to base_out[seg*128 + col].
__global__ __launch_bounds__(256, 2) void mlp3_k(
    const float* __restrict__ l_cur, const float* __restrict__ c_cur,
    const unsigned short* __restrict__ wt_hi, const unsigned short* __restrict__ wt_lo,
    const float* __restrict__ bb,
    const float* __restrict__ invsq_l, const float* __restrict__ invsq_c,
    bf16* __restrict__ l_msg, bf16* __restrict__ c_msg, bf16* __restrict__ l2lb,
    int nL, int nC, float* __restrict__ base_out) {
    __shared__ char smem[66048];
    unsigned short (*a_hi)[40] = (unsigned short(*)[40])(smem);
    unsigned short (*a_lo)[40] = (unsigned short(*)[40])(smem + 10240);
    unsigned short (*b_hi)[40] = (unsigned short(*)[40])(smem + 20480);
    unsigned short (*b_lo)[40] = (unsigned short(*)[40])(smem + 30720);
    unsigned short* h_hi = (unsigned short*)(smem);          // phase 2 aliases tiles
    unsigned short* h_lo = (unsigned short*)(smem + 32768);
    float* scv = (float*)(smem + 65536);                     // 128 floats, non-aliased

    int b = blockIdx.x, seg, tile;
    if (b < nL)           { seg = 0; tile = b; }
    else if (b < nL + nC) { seg = 1; tile = b - nL; }
    else                  { seg = 2; tile = b - nL - nC; }
    const float* A = (seg == 1) ? c_cur : l_cur;
    bf16* outp = (seg == 0) ? l_msg : (seg == 1) ? c_msg : l2lb;
    const float* invsq = (seg == 0) ? invsq_l : (seg == 1) ? invsq_c : nullptr;
    const unsigned short* W1h = wt_hi + seg * 32768;
    const unsigned short* W1l = wt_lo + seg * 32768;
    const unsigned short* W2h = W1h + 16384;
    const unsigned short* W2l = W1l + 16384;
    const float* b1v = bb + seg * 256;
    const float* b2v = b1v + 128;
    const int swap = (seg == 2);

    const int t = threadIdx.x;
    const int br0 = tile * 128;
    const int w = t >> 6, lane = t & 63;
    const int wr = w >> 1, wc = w & 1;
    const int quad = lane >> 4, cl = lane & 15;

    if (t < 128) scv[t] = invsq ? invsq[br0 + t] : 1.0f;

    f32x4 acc[4][4];
#pragma unroll
    for (int i = 0; i < 4; i++)
#pragma unroll
        for (int j = 0; j < 4; j++) acc[i][j] = (f32x4){0.f, 0.f, 0.f, 0.f};

    // ---- phase 1: h = A @ W1 ----
    for (int kt = 0; kt < 128; kt += 32) {
#pragma unroll
        for (int i = 0; i < 4; i++) {
            int f = t + 256 * i;
            int r = f >> 3, kq = f & 7;
            int gr = br0 + r;
            if (swap) gr ^= 1;
            const float4 v = *(const float4*)&A[(size_t)gr * D_ + kt + 4 * kq];
            unsigned short h0, l0, h1, l1, h2, l2, h3, l3;
            split2(v.x, h0, l0); split2(v.y, h1, l1);
            split2(v.z, h2, l2); split2(v.w, h3, l3);
            *(ushort4*)&a_hi[r][4 * kq] = make_ushort4(h0, h1, h2, h3);
            *(ushort4*)&a_lo[r][4 * kq] = make_ushort4(l0, l1, l2, l3);
            *(ushort4*)&b_hi[r][4 * kq] = *(const ushort4*)&W1h[(size_t)r * 128 + kt + 4 * kq];
            *(ushort4*)&b_lo[r][4 * kq] = *(const ushort4*)&W1l[(size_t)r * 128 + kt + 4 * kq];
        }
        __syncthreads();
        short8 af_h[4], af_l[4];
#pragma unroll
        for (int i = 0; i < 4; i++) {
            int row = 64 * wr + 16 * i + cl;
            af_h[i] = *(const short8*)&a_hi[row][quad * 8];
            af_l[i] = *(const short8*)&a_lo[row][quad * 8];
        }
#pragma unroll
        for (int j = 0; j < 4; j++) {
            int col = 64 * wc + 16 * j + cl;
            short8 bf_h = *(const short8*)&b_hi[col][quad * 8];
            short8 bf_l = *(const short8*)&b_lo[col][quad * 8];
#pragma unroll
            for (int i = 0; i < 4; i++) {
                acc[i][j] = __builtin_amdgcn_mfma_f32_16x16x32_bf16(af_h[i], bf_h, acc[i][j], 0, 0, 0);
                acc[i][j] = __builtin_amdgcn_mfma_f32_16x16x32_bf16(af_h[i], bf_l, acc[i][j], 0, 0, 0);
                acc[i][j] = __builtin_amdgcn_mfma_f32_16x16x32_bf16(af_l[i], bf_h, acc[i][j], 0, 0, 0);
            }
        }
        __syncthreads();
    }
    // h epilogue: bias + relu + split -> swizzled LDS. C/D: col=cl, row=quad*4+reg.
#pragma unroll
    for (int j = 0; j < 4; j++) {
        int col = 64 * wc + 16 * j + cl;
        float bv = b1v[col];
        int g = col >> 3, go = col & 7;
#pragma unroll
        for (int i = 0; i < 4; i++) {
            int rloc = 64 * wr + 16 * i + quad * 4;
#pragma unroll
            for (int rg = 0; rg < 4; rg++) {
                float v = fmaxf(acc[i][j][rg] + bv, 0.0f);
                unsigned short hh, ll;
                split2(v, hh, ll);
                int r = rloc + rg;
                int off = r * 128 + ((g ^ (r & 15)) << 3) + go;
                h_hi[off] = hh;
                h_lo[off] = ll;
            }
        }
    }
    __syncthreads();
    // ---- phase 2: out = (h @ W2 + b2) * scv -> bf16 ----
#pragma unroll
    for (int i = 0; i < 4; i++)
#pragma unroll
        for (int j = 0; j < 4; j++) acc[i][j] = (f32x4){0.f, 0.f, 0.f, 0.f};

    for (int kt = 0; kt < 128; kt += 32) {
        short8 af_h[4], af_l[4];
        int gbase = (kt >> 3) + quad;
#pragma unroll
        for (int i = 0; i < 4; i++) {
            int r = 64 * wr + 16 * i + cl;
            int off = r * 128 + ((gbase ^ cl) << 3);
            af_h[i] = *(const short8*)&h_hi[off];
            af_l[i] = *(const short8*)&h_lo[off];
        }
#pragma unroll
        for (int j = 0; j < 4; j++) {
            int col = 64 * wc + 16 * j + cl;
            const short8 bf_h = *(const short8*)&W2h[(size_t)col * 128 + kt + quad * 8];
            const short8 bf_l = *(const short8*)&W2l[(size_t)col * 128 + kt + quad * 8];
#pragma unroll
            for (int i = 0; i < 4; i++) {
                acc[i][j] = __builtin_amdgcn_mfma_f32_16x16x32_bf16(af_h[i], bf_h, acc[i][j], 0, 0, 0);
                acc[i][j] = __builtin_amdgcn_mfma_f32_16x16x32_bf16(af_h[i], bf_l, acc[i][j], 0, 0, 0);
                acc[i][j] = __builtin_amdgcn_mfma_f32_16x16x32_bf16(af_l[i], bf_h, acc[i][j], 0, 0, 0);
            }
        }
    }
#pragma unroll
    for (int j = 0; j < 4; j++) {
        int col = 64 * wc + 16 * j + cl;
        float bv = b2v[col];
        if (base_out && w < 2 && lane < 16)
            base_out[seg * 128 + col] = acc[0][j][0] + bv;   // row 0, pre-scale fp32
#pragma unroll
        for (int i = 0; i < 4; i++) {
            int rloc = 64 * wr + 16 * i + quad * 4;
#pragma unroll
            for (int rg = 0; rg < 4; rg++)
                outp[(size_t)(br0 + rloc + rg) * D_ + col] =
                    __float2bfloat16((acc[i][j][rg] + bv) * scv[rloc + rg]);
        }
    }
}

// ---------- fused update GEMMs; 128-row tiles (EXACT round-0 structure) ----------
template <int FINAL>
__global__ __launch_bounds__(256, 2) void update_k(
    const float* __restrict__ l_cur, const float* __restrict__ c_cur,
    const float* __restrict__ laggr, const float* __restrict__ caggr,
    const bf16* __restrict__ l2lb,
    const unsigned short* __restrict__ wt_hi, const unsigned short* __restrict__ wt_lo,
    const float* __restrict__ bb,
    float* __restrict__ c_nxt, float* __restrict__ l_nxt,
    void* __restrict__ dout, const int* __restrict__ flags) {
    __shared__ unsigned short a_hi[128][40], a_lo[128][40];
    __shared__ unsigned short b_hi[128][40], b_lo[128][40];
    const int t = threadIdx.x;
    int b = blockIdx.x;
    const bool cseg = (!FINAL) && (b < 256);
    const int tile = (FINAL || cseg) ? b : b - 256;
    const int K = cseg ? 256 : 384;
    const float* A0 = cseg ? c_cur : l_cur;
    const float* A1 = cseg ? caggr : laggr;
    const unsigned short* Wh = wt_hi + (cseg ? 98304 : 131072);
    const unsigned short* Wl = wt_lo + (cseg ? 98304 : 131072);
    const float* bias = bb + (cseg ? 768 : 896);
    const int br0 = tile * 128;
    const int w = t >> 6, lane = t & 63;
    const int wr = w >> 1, wc = w & 1;
    const int quad = lane >> 4, cl = lane & 15;

    f32x4 acc[4][4];
#pragma unroll
    for (int i = 0; i < 4; i++)
#pragma unroll
        for (int j = 0; j < 4; j++) acc[i][j] = (f32x4){0.f, 0.f, 0.f, 0.f};

    for (int kt = 0; kt < K; kt += 32) {
        const bool haslo = (kt < 256);
        const int koff = kt & 127;
#pragma unroll
        for (int i = 0; i < 4; i++) {
            int f = t + 256 * i;
            int r = f >> 3, kq = f & 7;
            if (haslo) {
                const float* As = (kt < 128) ? A0 : A1;
                const float4 v = *(const float4*)&As[(size_t)(br0 + r) * D_ + koff + 4 * kq];
                unsigned short h0, l0, h1, l1, h2, l2, h3, l3;
                split2(v.x, h0, l0); split2(v.y, h1, l1);
                split2(v.z, h2, l2); split2(v.w, h3, l3);
                *(ushort4*)&a_hi[r][4 * kq] = make_ushort4(h0, h1, h2, h3);
                *(ushort4*)&a_lo[r][4 * kq] = make_ushort4(l0, l1, l2, l3);
            } else {
                *(ushort4*)&a_hi[r][4 * kq] =
                    *(const ushort4*)&l2lb[(size_t)(br0 + r) * D_ + koff + 4 * kq];
            }
            *(ushort4*)&b_hi[r][4 * kq] = *(const ushort4*)&Wh[(size_t)r * K + kt + 4 * kq];
            *(ushort4*)&b_lo[r][4 * kq] = *(const ushort4*)&Wl[(size_t)r * K + kt + 4 * kq];
        }
        __syncthreads();
        short8 af_h[4], af_l[4];
#pragma unroll
        for (int i = 0; i < 4; i++) {
            int row = 64 * wr + 16 * i + cl;
            af_h[i] = *(const short8*)&a_hi[row][quad * 8];
            if (haslo) af_l[i] = *(const short8*)&a_lo[row][quad * 8];
        }
#pragma unroll
        for (int j = 0; j < 4; j++) {
            int col = 64 * wc + 16 * j + cl;
            short8 bf_h = *(const short8*)&b_hi[col][quad * 8];
            short8 bf_l = *(const short8*)&b_lo[col][quad * 8];
#pragma unroll
            for (int i = 0; i < 4; i++) {
                acc[i][j] = __builtin_amdgcn_mfma_f32_16x16x32_bf16(af_h[i], bf_h, acc[i][j], 0, 0, 0);
                acc[i][j] = __builtin_amdgcn_mfma_f32_16x16x32_bf16(af_h[i], bf_l, acc[i][j], 0, 0, 0);
                if (haslo)
                    acc[i][j] = __builtin_amdgcn_mfma_f32_16x16x32_bf16(af_l[i], bf_h, acc[i][j], 0, 0, 0);
            }
        }
        __syncthreads();
    }
    const int f32out = FINAL ? flags[0] : 1;
#pragma unroll
    for (int j = 0; j < 4; j++) {
        int col = 64 * wc + 16 * j + cl;
        float bv = bias[col];
#pragma unroll
        for (int i = 0; i < 4; i++) {
            int rbase = br0 + 64 * wr + 16 * i + quad * 4;
#pragma unroll
            for (int rg = 0; rg < 4; rg++) {
                float v = acc[i][j][rg] + bv;
                size_t idx = (size_t)(rbase + rg) * D_ + col;
                if (FINAL) {
                    if (f32out) ((float*)dout)[idx] = v;
                    else        ((bf16*)dout)[idx] = __float2bfloat16(v);
                } else {
                    (cseg ? c_nxt : l_nxt)[idx] = v;
                }
            }
        }
    }
}

extern "C" void kernel_launch(void* const* d_in, const int* in_sizes, int n_in,
                              void* d_out, int out_size, void* d_ws, size_t ws_size,
                              hipStream_t stream) {
    const int* li_raw = (const int*)d_in[0];
    const int* ci_raw = (const int*)d_in[1];

    // ---- workspace layout (flags after cdegi -> one zeroing memset) ----
    float* ws = (float*)d_ws;
    float* lbuf0 = ws;                               // L*D
    float* lbuf1 = lbuf0 + (size_t)L_ * D_;          // L*D  (doubles as bf16 l_msg)
    float* l2lb  = lbuf1 + (size_t)L_ * D_;          // L*D  (bf16 l2l messages)
    float* laggr = l2lb + (size_t)L_ * D_;           // L*D
    float* cbuf0 = laggr + (size_t)L_ * D_;          // C*D
    float* cbuf1 = cbuf0 + (size_t)C_ * D_;          // C*D  (doubles as bf16 c_msg)
    float* caggr = cbuf1 + (size_t)C_ * D_;          // C*D
    float* invsq_l = caggr + (size_t)C_ * D_;        // L
    float* invsq_c = invsq_l + L_;                   // C
    float* bb    = invsq_c + C_;                     // 1024 bias floats
    unsigned short* wt_hi = (unsigned short*)(bb + 1024);   // 180224 ushorts
    unsigned short* wt_lo = wt_hi + 180224;                 // 180224 ushorts
    int*   li    = (int*)(wt_lo + 180224);           // E
    int*   ci    = li + E_;                          // E
    int*   l_other = ci + E_;                        // E
    int*   c_other = l_other + E_;                   // E
    int*   ldegi = c_other + E_;                     // L
    int*   cdegi = ldegi + L_;                       // C
    int*   flags = cdegi + C_;                       // 2  (contiguous with deg arrays)
    int*   lptr  = flags + 2;                        // L
    int*   cptr  = lptr + L_;                        // C
    int*   lcur  = cptr + C_;                        // L
    int*   ccur  = lcur + L_;                        // C
    int*   bsumL = ccur + C_;                        // 256
    int*   bsumC = bsumL + 256;                      // 128
    float* baseb = (float*)(bsumC + 128);            // 384 fp32 (it=0 MLP base rows)
    float* ucbuf = baseb + 384;                      // 384 fp32 (it=0 update consts)

    // --- one memset zeroes degrees + flags; then dtype detection ---
    hipMemsetAsync(ldegi, 0, ((size_t)(L_ + C_) + 2) * sizeof(int), stream);
    detect_k<<<16, 512, 0, stream>>>((const unsigned short*)d_in[4], li_raw, flags);

    // --- fused preamble: fixdeg + weight-split + tile-0 embedding-init ---
    prep_k<<<2788, 256, 0, stream>>>(
        li_raw, ci_raw, li, ci, ldegi, cdegi,
        d_in[4], d_in[6], d_in[8], d_in[10], d_in[12], d_in[14], d_in[16], d_in[18],
        d_in[5], d_in[7], d_in[9], d_in[11], d_in[13], d_in[15], d_in[17], d_in[19],
        wt_hi, wt_lo, bb,
        d_in[2], d_in[3], lbuf0, cbuf0, flags);

    // --- CSR build ---
    scan1b_k<<<384, 256, 0, stream>>>(ldegi, cdegi, lptr, cptr, bsumL, bsumC);
    scan3b_k<<<384, 256, 0, stream>>>(lptr, cptr, bsumL, bsumC, lcur, ccur,
                                      ldegi, cdegi, invsq_l, invsq_c);
    place_k<<<E_ / 256, 256, 0, stream>>>(li, ci, lcur, ccur, l_other, c_other);

    float* l_cur = lbuf0; float* l_nxt = lbuf1;
    float* c_cur = cbuf0; float* c_nxt = cbuf1;

    const int nL = L_ / 128, nC = C_ / 128;

    // ---- it=0: embeddings row-uniform -> 3-block mlp3 captures base rows;
    //      gather0 synthesizes the rank-1 messages in-register (no message
    //      materialization); bcast writes only l2lb rows 0..127 for uconst;
    //      update0 runs only the aggregate K-range ----
    mlp3_k<<<3, 256, 0, stream>>>(
        l_cur, c_cur, wt_hi, wt_lo, bb, invsq_l, invsq_c,
        (bf16*)l_nxt, (bf16*)c_nxt, (bf16*)l2lb, 1, 1, baseb);
    bcast_k<<<8, 256, 0, stream>>>(baseb, (bf16*)l2lb);
    uconst_k<<<2, 256, 0, stream>>>(
        l_cur, c_cur, (const bf16*)l2lb, wt_hi, wt_lo, ucbuf);
    gather0_k<<<(C_ + L_) / 16, 256, 0, stream>>>(
        cptr, cdegi, c_other, baseb, invsq_l, invsq_c, caggr,
        lptr, ldegi, l_other, laggr, C_);
    update0_k<<<768, 256, 0, stream>>>(
        laggr, caggr, wt_hi, wt_lo, bb, ucbuf, c_nxt, l_nxt);
    { float* tmp = l_cur; l_cur = l_nxt; l_nxt = tmp;
      tmp = c_cur; c_cur = c_nxt; c_nxt = tmp; }

    // ---- it=1,2: full pipeline ----
    for (int it = 1; it < 3; it++) {
        mlp3_k<<<2 * nL + nC, 256, 0, stream>>>(
            l_cur, c_cur, wt_hi, wt_lo, bb, invsq_l, invsq_c,
            (bf16*)l_nxt, (bf16*)c_nxt, (bf16*)l2lb, nL, nC, nullptr);
        gather2_k<<<(C_ + L_) / 16, 256, 0, stream>>>(
            cptr, cdegi, c_other, (const unsigned int*)l_nxt, invsq_c, caggr,
            lptr, ldegi, l_other, (const unsigned int*)c_nxt, invsq_l, laggr, C_);
        update_k<0><<<768, 256, 0, stream>>>(
            l_cur, c_cur, laggr, caggr, (const bf16*)l2lb, wt_hi, wt_lo, bb,
            c_nxt, l_nxt, nullptr, flags);
        float* tmp = l_cur; l_cur = l_nxt; l_nxt = tmp;
        tmp = c_cur; c_cur = c_nxt; c_nxt = tmp;
    }
    // --- final iteration: c-update dead -> skip l2c MLP, c-gather, c-update;
    //     fuse output dtype conversion into the l-update epilogue ---
    mlp3_k<<<nC + nL, 256, 0, stream>>>(
        l_cur, c_cur, wt_hi, wt_lo, bb, invsq_l, invsq_c,
        (bf16*)l_nxt, (bf16*)c_nxt, (bf16*)l2lb, 0, nC, nullptr);
    gather2_k<<<L_ / 16, 256, 0, stream>>>(
        cptr, cdegi, c_other, (const unsigned int*)l_nxt, invsq_c, caggr,
        lptr, ldegi, l_other, (const unsigned int*)c_nxt, invsq_l, laggr, 0);
    update_k<1><<<512, 256, 0, stream>>>(
        l_cur, c_cur, laggr, caggr, (const bf16*)l2lb, wt_hi, wt_lo, bb,
        nullptr, nullptr, d_out, flags);
}